// Round 3
// baseline (1214.089 us; speedup 1.0000x reference)
//
#include <hip/hip_runtime.h>
#include <cstdint>
#include <cstddef>

using u16 = unsigned short;
using u32 = unsigned int;

// ---------------- helpers ----------------
__device__ __forceinline__ float bf2f(u16 u){
  union { u32 i; float f; } x; x.i = ((u32)u) << 16; return x.f;
}
__device__ __forceinline__ u16 f2bf(float f){
  union { float f; u32 i; } x; x.f = f;
  u32 r = x.i + 0x7fffu + ((x.i >> 16) & 1u);
  return (u16)(r >> 16);
}
__device__ __forceinline__ float gelu_f(float x){
  return 0.5f * x * (1.0f + erff(x * 0.70710678118654752f));
}
__device__ __forceinline__ void unpack16(const u16* __restrict__ p, float* f){
  uint4 a = *(const uint4*)p;
  uint4 b = *(const uint4*)(p + 8);
  u32 ua[8] = {a.x, a.y, a.z, a.w, b.x, b.y, b.z, b.w};
#pragma unroll
  for (int i = 0; i < 8; ++i){
    f[2*i]   = bf2f((u16)(ua[i] & 0xffffu));
    f[2*i+1] = bf2f((u16)(ua[i] >> 16));
  }
}

typedef __bf16 bf16x8 __attribute__((ext_vector_type(8)));
typedef float  f32x4  __attribute__((ext_vector_type(4)));

// ---------------- weight transpose + cast: src fp32 [R,C] -> dst bf16 [C,R] ----------------
__global__ __launch_bounds__(256) void k_transpose(const float* __restrict__ src,
                                                   u16* __restrict__ dst, int R, int C){
  __shared__ u16 tile[32][33];
  int bx = blockIdx.x * 32;   // col tile in src
  int by = blockIdx.y * 32;   // row tile in src
  int tx = threadIdx.x & 31;
  int ty = threadIdx.x >> 5;  // 0..7
  for (int r = ty; r < 32; r += 8)
    tile[r][tx] = f2bf(src[(size_t)(by + r) * C + bx + tx]);
  __syncthreads();
  for (int r = ty; r < 32; r += 8)
    dst[(size_t)(bx + r) * R + by + tx] = tile[tx][r];
}

// ---------------- layernorm over last dim (cols = 1024 or 512), optional gelu, bf16 out ----------------
template<bool IN_F32, bool DO_GELU>
__global__ __launch_bounds__(256) void k_layernorm(const void* __restrict__ inp,
    const float* __restrict__ w, const float* __restrict__ bsh,
    u16* __restrict__ out, int cols, float eps){
  int row = blockIdx.x, t = threadIdx.x;
  size_t base = (size_t)row * cols;
  const float* inf = (const float*)inp;
  const u16*  inb = (const u16*)inp;
  float v[4];
  int ep = cols >> 8;     // 4 or 2 elements per thread
  float s = 0.f, ss = 0.f;
  for (int e = 0; e < ep; ++e){
    int idx = t + (e << 8);
    float x = IN_F32 ? inf[base + idx] : bf2f(inb[base + idx]);
    v[e] = x; s += x; ss += x * x;
  }
#pragma unroll
  for (int off = 1; off < 64; off <<= 1){
    s  += __shfl_xor(s, off, 64);
    ss += __shfl_xor(ss, off, 64);
  }
  __shared__ float red[8];
  int wv = t >> 6;
  if ((t & 63) == 0){ red[wv] = s; red[4 + wv] = ss; }
  __syncthreads();
  s  = red[0] + red[1] + red[2] + red[3];
  ss = red[4] + red[5] + red[6] + red[7];
  float inv = 1.f / (float)cols;
  float mean = s * inv;
  float var = ss * inv - mean * mean;
  float rs = rsqrtf(var + eps);
  for (int e = 0; e < ep; ++e){
    int idx = t + (e << 8);
    float y = (v[e] - mean) * rs * w[idx] + bsh[idx];
    if (DO_GELU) y = gelu_f(y);
    out[base + idx] = f2bf(y);
  }
}

// ---------------- final: out(fp32) = x2f + LN(c3; ln3) , cols=1024 ----------------
__global__ __launch_bounds__(256) void k_final(const u16* __restrict__ c3,
    const float* __restrict__ x2f, const float* __restrict__ w,
    const float* __restrict__ bsh, float* __restrict__ out){
  int row = blockIdx.x, t = threadIdx.x;
  size_t base = (size_t)row << 10;
  float v[4];
  float s = 0.f, ss = 0.f;
#pragma unroll
  for (int e = 0; e < 4; ++e){
    int idx = t + (e << 8);
    float x = bf2f(c3[base + idx]);
    v[e] = x; s += x; ss += x * x;
  }
#pragma unroll
  for (int off = 1; off < 64; off <<= 1){
    s  += __shfl_xor(s, off, 64);
    ss += __shfl_xor(ss, off, 64);
  }
  __shared__ float red[8];
  int wv = t >> 6;
  if ((t & 63) == 0){ red[wv] = s; red[4 + wv] = ss; }
  __syncthreads();
  s  = red[0] + red[1] + red[2] + red[3];
  ss = red[4] + red[5] + red[6] + red[7];
  float mean = s * (1.f/1024.f);
  float var = ss * (1.f/1024.f) - mean * mean;
  float rs = rsqrtf(var + 1e-6f);
#pragma unroll
  for (int e = 0; e < 4; ++e){
    int idx = t + (e << 8);
    float y = (v[e] - mean) * rs * w[idx] + bsh[idx];
    out[base + idx] = x2f[base + idx] + y;
  }
}

// ---------------- MFMA GEMM: C[M,N] = A[M,K](bf16) * Bt[N,K]^T(bf16) (+fp32 bias/res, gelu) ----------------
// 128x128 tile, BK=32, 4 waves (2x2 of 64x64). uint4 register->LDS staging.
template<bool BIAS, bool GELU, bool RES, bool OUTB, bool OUTF>
__global__ __launch_bounds__(256, 2) void k_gemm(
    const u16* __restrict__ A, const u16* __restrict__ Bt,
    const float* __restrict__ bias, const float* __restrict__ resf,
    u16* __restrict__ outb, float* __restrict__ outf, int N, int K)
{
  __shared__ __align__(16) u16 As[128 * 32];
  __shared__ __align__(16) u16 Bs[128 * 32];
  int t = threadIdx.x, lane = t & 63, wv = t >> 6;
  int m0 = blockIdx.y << 7, n0 = blockIdx.x << 7;
  int wm = (wv >> 1) << 6, wn = (wv & 1) << 6;

  f32x4 acc[4][4];
  const f32x4 z4 = {0.f, 0.f, 0.f, 0.f};
#pragma unroll
  for (int i = 0; i < 4; ++i)
#pragma unroll
    for (int j = 0; j < 4; ++j) acc[i][j] = z4;

  // staging: lane -> (row = lane>>2, kchunk = lane&3); LDS byte addr = lane*16, conflict-free
  int srow = (wv << 5) + (lane >> 2);
  int skp  = (lane & 3) << 3;
  const u16* Ag = A  + (size_t)(m0 + srow) * K + skp;
  const u16* Bg = Bt + (size_t)(n0 + srow) * K + skp;
  const size_t rowskip = (size_t)16 * K;

  int fr = lane & 15, fq = (lane >> 4) << 3;  // fragment row / k-quad

  for (int k0 = 0; k0 < K; k0 += 32){
    uint4 a0 = *(const uint4*)(Ag + k0);
    uint4 a1 = *(const uint4*)(Ag + rowskip + k0);
    uint4 b0 = *(const uint4*)(Bg + k0);
    uint4 b1 = *(const uint4*)(Bg + rowskip + k0);
    *(uint4*)&As[(size_t)srow * 32 + skp]        = a0;
    *(uint4*)&As[(size_t)(srow + 16) * 32 + skp] = a1;
    *(uint4*)&Bs[(size_t)srow * 32 + skp]        = b0;
    *(uint4*)&Bs[(size_t)(srow + 16) * 32 + skp] = b1;
    __syncthreads();
    bf16x8 af[4], bfr[4];
#pragma unroll
    for (int i = 0; i < 4; ++i)
      af[i] = *(const bf16x8*)&As[(wm + i * 16 + fr) * 32 + fq];
#pragma unroll
    for (int j = 0; j < 4; ++j)
      bfr[j] = *(const bf16x8*)&Bs[(wn + j * 16 + fr) * 32 + fq];
#pragma unroll
    for (int i = 0; i < 4; ++i)
#pragma unroll
      for (int j = 0; j < 4; ++j)
        acc[i][j] = __builtin_amdgcn_mfma_f32_16x16x32_bf16(af[i], bfr[j], acc[i][j], 0, 0, 0);
    __syncthreads();
  }

  // epilogue: D row=(lane>>4)*4+r, col=lane&15 (verified m89/m91 layout)
  int rr = (lane >> 4) << 2;
  int cc = lane & 15;
#pragma unroll
  for (int i = 0; i < 4; ++i)
#pragma unroll
    for (int j = 0; j < 4; ++j){
      int gc = n0 + wn + j * 16 + cc;
      float bb = BIAS ? bias[gc] : 0.f;
#pragma unroll
      for (int r = 0; r < 4; ++r){
        int gr = m0 + wm + i * 16 + rr + r;
        size_t idx = (size_t)gr * N + gc;
        float vv = acc[i][j][r] + bb;
        if (RES) vv += resf[idx];          // read-before-write: outf may alias resf
        if (GELU) vv = gelu_f(vv);
        if (OUTF) outf[idx] = vv;
        if (OUTB) outb[idx] = f2bf(vv);
      }
    }
}

// ---------------- fused attention (online softmax, rel-pos bias) ----------------
// grid: (13 q-tiles of 64, B*NH). 256 thr: qg=t>>3 handles 2 queries, part=t&7 handles 8 keys / 8 dims.
__global__ __launch_bounds__(256, 2) void k_attn(const u16* __restrict__ qkv,
    const float* __restrict__ relh, const float* __restrict__ relw,
    u16* __restrict__ out)
{
  __shared__ float q_s[64][65];
  __shared__ float kT_s[64][64];   // [d][j]
  __shared__ float v_s[64][64];    // [j][d]
  __shared__ float p_s[64][65];
  __shared__ float bh_s[64][28];
  __shared__ float bw_s[64][28];

  const int t = threadIdx.x;
  const int bnh = blockIdx.y, b = bnh >> 4, nh = bnh & 15;
  const int q0 = blockIdx.x << 6;
  const size_t rowbase = (size_t)b * 784;

  // load Q tile
  {
    int row = t >> 2, d0 = (t & 3) << 4;
    int qrow = q0 + row;
    float f[16];
    if (qrow < 784){
      unpack16(qkv + (rowbase + qrow) * 3072 + nh * 64 + d0, f);
    } else {
#pragma unroll
      for (int e = 0; e < 16; ++e) f[e] = 0.f;
    }
#pragma unroll
    for (int e = 0; e < 16; ++e) q_s[row][d0 + e] = f[e];
  }
  __syncthreads();

  // bias tables: bh[q][kh] = q . rel_h[hq-kh+27],  bw[q][kw] = q . rel_w[wq-kw+27]
  for (int idx = t; idx < 3584; idx += 256){
    int which = idx / 1792, rem = idx % 1792;
    int qq = rem / 28, kk = rem % 28;
    int qrow = q0 + qq; if (qrow > 783) qrow = 783;
    int hq = qrow / 28, wq = qrow % 28;
    const float* R = which ? (relw + (size_t)(wq - kk + 27) * 64)
                           : (relh + (size_t)(hq - kk + 27) * 64);
    float sum = 0.f;
    for (int d = 0; d < 64; ++d) sum += q_s[qq][d] * R[d];
    if (which) bw_s[qq][kk] = sum; else bh_s[qq][kk] = sum;
  }
  __syncthreads();

  const int qg = t >> 3, part = t & 7, part8 = part << 3;
  const int ql0 = qg << 1, ql1 = ql0 + 1;
  float m0r = -1e9f, m1r = -1e9f, l0 = 0.f, l1 = 0.f;
  float o0[8], o1[8];
#pragma unroll
  for (int e = 0; e < 8; ++e){ o0[e] = 0.f; o1[e] = 0.f; }

  for (int kt = 0; kt < 13; ++kt){
    int j0 = kt << 6;
    __syncthreads();   // protect kT_s/v_s/p_s from previous tile readers
    {
      int row = t >> 2, d0 = (t & 3) << 4;
      int krow = j0 + row;
      float kf[16], vf[16];
      if (krow < 784){
        const u16* kp = qkv + (rowbase + krow) * 3072 + 1024 + nh * 64 + d0;
        unpack16(kp, kf);
        unpack16(kp + 1024, vf);
      } else {
#pragma unroll
        for (int e = 0; e < 16; ++e){ kf[e] = 0.f; vf[e] = 0.f; }
      }
#pragma unroll
      for (int e = 0; e < 16; ++e) kT_s[d0 + e][row] = kf[e];
#pragma unroll
      for (int e = 0; e < 16; ++e) v_s[row][d0 + e] = vf[e];
    }
    __syncthreads();

    // scores for 2 queries x 8 keys
    float dv0[8], dv1[8];
#pragma unroll
    for (int e = 0; e < 8; ++e){ dv0[e] = 0.f; dv1[e] = 0.f; }
#pragma unroll 4
    for (int d = 0; d < 64; ++d){
      float qa = q_s[ql0][d];
      float qb = q_s[ql1][d];
      float4 k0 = *(const float4*)&kT_s[d][part8];
      float4 k1 = *(const float4*)&kT_s[d][part8 + 4];
      dv0[0] += qa * k0.x; dv0[1] += qa * k0.y; dv0[2] += qa * k0.z; dv0[3] += qa * k0.w;
      dv0[4] += qa * k1.x; dv0[5] += qa * k1.y; dv0[6] += qa * k1.z; dv0[7] += qa * k1.w;
      dv1[0] += qb * k0.x; dv1[1] += qb * k0.y; dv1[2] += qb * k0.z; dv1[3] += qb * k0.w;
      dv1[4] += qb * k1.x; dv1[5] += qb * k1.y; dv1[6] += qb * k1.z; dv1[7] += qb * k1.w;
    }
    float sc0[8], sc1[8];
    float mx0 = -1e9f, mx1 = -1e9f;
#pragma unroll
    for (int jj = 0; jj < 8; ++jj){
      int jg = j0 + part8 + jj;
      if (jg < 784){
        int hj = jg / 28, wj = jg % 28;
        sc0[jj] = 0.125f * dv0[jj] + bh_s[ql0][hj] + bw_s[ql0][wj];
        sc1[jj] = 0.125f * dv1[jj] + bh_s[ql1][hj] + bw_s[ql1][wj];
      } else { sc0[jj] = -1e9f; sc1[jj] = -1e9f; }
      mx0 = fmaxf(mx0, sc0[jj]); mx1 = fmaxf(mx1, sc1[jj]);
    }
#pragma unroll
    for (int off = 1; off < 8; off <<= 1){
      mx0 = fmaxf(mx0, __shfl_xor(mx0, off, 64));
      mx1 = fmaxf(mx1, __shfl_xor(mx1, off, 64));
    }
    float mn0 = fmaxf(m0r, mx0), mn1 = fmaxf(m1r, mx1);
    float a0 = __expf(m0r - mn0), a1 = __expf(m1r - mn1);
    float s0 = 0.f, s1 = 0.f;
#pragma unroll
    for (int jj = 0; jj < 8; ++jj){
      sc0[jj] = __expf(sc0[jj] - mn0); s0 += sc0[jj];
      sc1[jj] = __expf(sc1[jj] - mn1); s1 += sc1[jj];
    }
#pragma unroll
    for (int off = 1; off < 8; off <<= 1){
      s0 += __shfl_xor(s0, off, 64);
      s1 += __shfl_xor(s1, off, 64);
    }
    l0 = l0 * a0 + s0; l1 = l1 * a1 + s1;
    m0r = mn0; m1r = mn1;
#pragma unroll
    for (int e = 0; e < 8; ++e){ o0[e] *= a0; o1[e] *= a1; }
#pragma unroll
    for (int jj = 0; jj < 8; ++jj){
      p_s[ql0][part8 + jj] = sc0[jj];
      p_s[ql1][part8 + jj] = sc1[jj];
    }
    __syncthreads();
    // PV
#pragma unroll 4
    for (int j = 0; j < 64; ++j){
      float pa = p_s[ql0][j], pb = p_s[ql1][j];
      float4 v0 = *(const float4*)&v_s[j][part8];
      float4 v1 = *(const float4*)&v_s[j][part8 + 4];
      o0[0] += pa * v0.x; o0[1] += pa * v0.y; o0[2] += pa * v0.z; o0[3] += pa * v0.w;
      o0[4] += pa * v1.x; o0[5] += pa * v1.y; o0[6] += pa * v1.z; o0[7] += pa * v1.w;
      o1[0] += pb * v0.x; o1[1] += pb * v0.y; o1[2] += pb * v0.z; o1[3] += pb * v0.w;
      o1[4] += pb * v1.x; o1[5] += pb * v1.y; o1[6] += pb * v1.z; o1[7] += pb * v1.w;
    }
  }

  float i0 = 1.f / l0, i1 = 1.f / l1;
  int r0 = q0 + ql0, r1 = q0 + ql1;
  if (r0 < 784){
    u16* dp = out + (rowbase + r0) * 1024 + nh * 64 + part8;
#pragma unroll
    for (int e = 0; e < 8; ++e) dp[e] = f2bf(o0[e] * i0);
  }
  if (r1 < 784){
    u16* dp = out + (rowbase + r1) * 1024 + nh * 64 + part8;
#pragma unroll
    for (int e = 0; e < 8; ++e) dp[e] = f2bf(o1[e] * i1);
  }
}

// ---------------- im2col for 3x3 pad-1 conv: g[B,28,28,512](bf16) -> im[6272, 4608] ----------------
__global__ __launch_bounds__(256) void k_im2col(const u16* __restrict__ g, u16* __restrict__ im){
  int idx = blockIdx.x * 256 + threadIdx.x;   // one 8-channel chunk
  int p  = idx / 576;
  int c8 = idx - p * 576;
  int k0 = c8 << 3;
  int t9 = k0 >> 9;
  int ci = k0 & 511;
  int ky = t9 / 3, kx = t9 - ky * 3;
  int bb = p / 784;
  int s = p - bb * 784;
  int h = s / 28, w = s - h * 28;
  int hh = h + ky - 1, ww = w + kx - 1;
  uint4 val = make_uint4(0u, 0u, 0u, 0u);
  if ((unsigned)hh < 28u && (unsigned)ww < 28u)
    val = *(const uint4*)&g[(((size_t)(bb * 28 + hh)) * 28 + ww) * 512 + ci];
  *(uint4*)&im[(size_t)p * 4608 + k0] = val;
}

// ---------------- orchestration ----------------
extern "C" void kernel_launch(void* const* d_in, const int* in_sizes, int n_in,
                              void* d_out, int out_size, void* d_ws, size_t ws_size,
                              hipStream_t stream)
{
  (void)in_sizes; (void)n_in; (void)out_size; (void)ws_size;
  // ALL inputs are float32 per the reference (R2 post-mortem: bf16 misread caused NaN).
  const float* x      = (const float*)d_in[0];
  const float* n1w    = (const float*)d_in[1];
  const float* n1b    = (const float*)d_in[2];
  const float* qkv_w  = (const float*)d_in[3];
  const float* qkv_b  = (const float*)d_in[4];
  const float* proj_w = (const float*)d_in[5];
  const float* proj_b = (const float*)d_in[6];
  const float* rel_h  = (const float*)d_in[7];
  const float* rel_w  = (const float*)d_in[8];
  const float* n2w    = (const float*)d_in[9];
  const float* n2b    = (const float*)d_in[10];
  const float* fc1_w  = (const float*)d_in[11];
  const float* fc1_b  = (const float*)d_in[12];
  const float* fc2_w  = (const float*)d_in[13];
  const float* fc2_b  = (const float*)d_in[14];
  const float* c1w    = (const float*)d_in[15];
  const float* l1w    = (const float*)d_in[16];
  const float* l1b    = (const float*)d_in[17];
  const float* c2w    = (const float*)d_in[18];
  const float* l2w    = (const float*)d_in[19];
  const float* l2b    = (const float*)d_in[20];
  const float* c3w    = (const float*)d_in[21];
  const float* l3w    = (const float*)d_in[22];
  const float* l3b    = (const float*)d_in[23];

  char* ws = (char*)d_ws;
  size_t off = 0;
  auto alloc = [&](size_t bytes) -> void* {
    void* p = ws + off; off += (bytes + 255) & ~(size_t)255; return p;
  };
  const size_t M = 6272;
  // bf16 transposed weights — 32.0 MB
  u16* qkvT  = (u16*)alloc((size_t)3072 * 1024 * 2);
  u16* projT = (u16*)alloc((size_t)1024 * 1024 * 2);
  u16* fc1T  = (u16*)alloc((size_t)4096 * 1024 * 2);
  u16* fc2T  = (u16*)alloc((size_t)1024 * 4096 * 2);
  u16* c1T   = (u16*)alloc((size_t)512 * 1024 * 2);
  u16* c2T   = (u16*)alloc((size_t)512 * 4608 * 2);
  u16* c3T   = (u16*)alloc((size_t)1024 * 512 * 2);
  // activations — ordered for aliasing; total ws ≈ 148 MB
  u16* qkvbuf = (u16*)alloc(M * 3072 * 2);   // 38.5 MB
  u16* attn   = (u16*)alloc(M * 1024 * 2);   // 12.8 MB (right after qkvbuf)
  u16* xn     = (u16*)alloc(M * 1024 * 2);   // 12.8 MB
  float* x1   = (float*)alloc(M * 1024 * 4); // 25.7 MB fp32
  u16* x2b    = (u16*)alloc(M * 1024 * 2);   // 12.8 MB
  u16* c1buf  = (u16*)alloc(M * 512 * 2);    // 6.4 MB
  u16* g1buf  = (u16*)alloc(M * 512 * 2);    // 6.4 MB
  // aliases (lifetime-checked):
  u16* hmlp   = qkvbuf;      // 51.38 MB = qkvbuf+attn exactly; both dead before fc1
  u16* im     = qkvbuf;      // 57.8 MB = qkvbuf+attn+part of xn; all dead before im2col
  u16* xn2    = xn;          // xn (LN1 out) dead after qkv GEMM
  float* x2f  = x1;          // fc2 reads x1 residual then overwrites same idx (same thread)
  u16* c2buf  = c1buf;       // c1 dead after LN+gelu
  u16* g2buf  = g1buf;       // g1 dead after im2col
  u16* c3buf  = attn;        // attn/im dead after conv2 GEMM

  dim3 blk(256);
  // weight transposes+casts ([K,N] fp32 -> [N,K] bf16)
  k_transpose<<<dim3(3072/32, 1024/32), blk, 0, stream>>>(qkv_w, qkvT, 1024, 3072);
  k_transpose<<<dim3(1024/32, 1024/32), blk, 0, stream>>>(proj_w, projT, 1024, 1024);
  k_transpose<<<dim3(4096/32, 1024/32), blk, 0, stream>>>(fc1_w, fc1T, 1024, 4096);
  k_transpose<<<dim3(1024/32, 4096/32), blk, 0, stream>>>(fc2_w, fc2T, 4096, 1024);
  k_transpose<<<dim3(512/32, 1024/32),  blk, 0, stream>>>(c1w, c1T, 1024, 512);
  k_transpose<<<dim3(512/32, 4608/32),  blk, 0, stream>>>(c2w, c2T, 4608, 512);
  k_transpose<<<dim3(1024/32, 512/32),  blk, 0, stream>>>(c3w, c3T, 512, 1024);

  // LN1 (fp32 in, bf16 out)
  k_layernorm<true,false><<<6272, blk, 0, stream>>>(x, n1w, n1b, xn, 1024, 1e-5f);
  // QKV: qkvbuf = xn @ qkv_w + b
  k_gemm<true,false,false,true,false><<<dim3(24,49), blk, 0, stream>>>(
      xn, qkvT, qkv_b, nullptr, qkvbuf, nullptr, 3072, 1024);
  // attention
  k_attn<<<dim3(13,128), blk, 0, stream>>>(qkvbuf, rel_h, rel_w, attn);
  // proj + residual (fp32 x) -> x1 fp32
  k_gemm<true,false,true,false,true><<<dim3(8,49), blk, 0, stream>>>(
      attn, projT, proj_b, x, nullptr, x1, 1024, 1024);
  // LN2 (fp32 in)
  k_layernorm<true,false><<<6272, blk, 0, stream>>>(x1, n2w, n2b, xn2, 1024, 1e-5f);
  // fc1 + gelu  (writes hmlp over dead qkvbuf+attn)
  k_gemm<true,true,false,true,false><<<dim3(32,49), blk, 0, stream>>>(
      xn2, fc1T, fc1_b, nullptr, hmlp, nullptr, 4096, 1024);
  // fc2 + residual(x1 fp32) -> x2b bf16 + x2f fp32 (x2f aliases x1; read-before-write)
  k_gemm<true,false,true,true,true><<<dim3(8,49), blk, 0, stream>>>(
      hmlp, fc2T, fc2_b, x1, x2b, x2f, 1024, 4096);
  // conv1 (1x1)
  k_gemm<false,false,false,true,false><<<dim3(4,49), blk, 0, stream>>>(
      x2b, c1T, nullptr, nullptr, c1buf, nullptr, 512, 1024);
  k_layernorm<false,true><<<6272, blk, 0, stream>>>(c1buf, l1w, l1b, g1buf, 512, 1e-6f);
  // conv2 (3x3) via im2col (im over dead hmlp/xn region)
  k_im2col<<<14112, blk, 0, stream>>>(g1buf, im);
  k_gemm<false,false,false,true,false><<<dim3(4,49), blk, 0, stream>>>(
      im, c2T, nullptr, nullptr, c2buf, nullptr, 512, 4608);
  k_layernorm<false,true><<<6272, blk, 0, stream>>>(c2buf, l2w, l2b, g2buf, 512, 1e-6f);
  // conv3 (1x1)  (c3buf over dead attn)
  k_gemm<false,false,false,true,false><<<dim3(8,49), blk, 0, stream>>>(
      g2buf, c3T, nullptr, nullptr, c3buf, nullptr, 1024, 512);
  // final: out(fp32) = x2f + LN(c3; ln3)
  k_final<<<6272, blk, 0, stream>>>(c3buf, x2f, l3w, l3b, (float*)d_out);
}

// Round 4
// 924.889 us; speedup vs baseline: 1.3127x; 1.3127x over previous
//
#include <hip/hip_runtime.h>
#include <cstdint>
#include <cstddef>

using u16 = unsigned short;
using u32 = unsigned int;

// ---------------- helpers ----------------
__device__ __forceinline__ float bf2f(u16 u){
  union { u32 i; float f; } x; x.i = ((u32)u) << 16; return x.f;
}
__device__ __forceinline__ u16 f2bf(float f){
  union { float f; u32 i; } x; x.f = f;
  u32 r = x.i + 0x7fffu + ((x.i >> 16) & 1u);
  return (u16)(r >> 16);
}
__device__ __forceinline__ float gelu_f(float x){
  return 0.5f * x * (1.0f + erff(x * 0.70710678118654752f));
}
__device__ __forceinline__ void unpack16(const u16* __restrict__ p, float* f){
  uint4 a = *(const uint4*)p;
  uint4 b = *(const uint4*)(p + 8);
  u32 ua[8] = {a.x, a.y, a.z, a.w, b.x, b.y, b.z, b.w};
#pragma unroll
  for (int i = 0; i < 8; ++i){
    f[2*i]   = bf2f((u16)(ua[i] & 0xffffu));
    f[2*i+1] = bf2f((u16)(ua[i] >> 16));
  }
}

typedef __bf16 bf16x8 __attribute__((ext_vector_type(8)));
typedef float  f32x4  __attribute__((ext_vector_type(4)));

// ---------------- weight transpose + cast: src fp32 [R,C] -> dst bf16 [C,R] ----------------
__global__ __launch_bounds__(256) void k_transpose(const float* __restrict__ src,
                                                   u16* __restrict__ dst, int R, int C){
  __shared__ u16 tile[32][33];
  int bx = blockIdx.x * 32;   // col tile in src
  int by = blockIdx.y * 32;   // row tile in src
  int tx = threadIdx.x & 31;
  int ty = threadIdx.x >> 5;  // 0..7
  for (int r = ty; r < 32; r += 8)
    tile[r][tx] = f2bf(src[(size_t)(by + r) * C + bx + tx]);
  __syncthreads();
  for (int r = ty; r < 32; r += 8)
    dst[(size_t)(bx + r) * R + by + tx] = tile[tx][r];
}

// ---------------- layernorm over last dim (cols = 1024 or 512), optional gelu, bf16 out ----------------
template<bool IN_F32, bool DO_GELU>
__global__ __launch_bounds__(256) void k_layernorm(const void* __restrict__ inp,
    const float* __restrict__ w, const float* __restrict__ bsh,
    u16* __restrict__ out, int cols, float eps){
  int row = blockIdx.x, t = threadIdx.x;
  size_t base = (size_t)row * cols;
  const float* inf = (const float*)inp;
  const u16*  inb = (const u16*)inp;
  float v[4];
  int ep = cols >> 8;     // 4 or 2 elements per thread
  float s = 0.f, ss = 0.f;
  for (int e = 0; e < ep; ++e){
    int idx = t + (e << 8);
    float x = IN_F32 ? inf[base + idx] : bf2f(inb[base + idx]);
    v[e] = x; s += x; ss += x * x;
  }
#pragma unroll
  for (int off = 1; off < 64; off <<= 1){
    s  += __shfl_xor(s, off, 64);
    ss += __shfl_xor(ss, off, 64);
  }
  __shared__ float red[8];
  int wv = t >> 6;
  if ((t & 63) == 0){ red[wv] = s; red[4 + wv] = ss; }
  __syncthreads();
  s  = red[0] + red[1] + red[2] + red[3];
  ss = red[4] + red[5] + red[6] + red[7];
  float inv = 1.f / (float)cols;
  float mean = s * inv;
  float var = ss * inv - mean * mean;
  float rs = rsqrtf(var + eps);
  for (int e = 0; e < ep; ++e){
    int idx = t + (e << 8);
    float y = (v[e] - mean) * rs * w[idx] + bsh[idx];
    if (DO_GELU) y = gelu_f(y);
    out[base + idx] = f2bf(y);
  }
}

// ---------------- final: out(fp32) = x2f + LN(c3; ln3) , cols=1024 ----------------
__global__ __launch_bounds__(256) void k_final(const u16* __restrict__ c3,
    const float* __restrict__ x2f, const float* __restrict__ w,
    const float* __restrict__ bsh, float* __restrict__ out){
  int row = blockIdx.x, t = threadIdx.x;
  size_t base = (size_t)row << 10;
  float v[4];
  float s = 0.f, ss = 0.f;
#pragma unroll
  for (int e = 0; e < 4; ++e){
    int idx = t + (e << 8);
    float x = bf2f(c3[base + idx]);
    v[e] = x; s += x; ss += x * x;
  }
#pragma unroll
  for (int off = 1; off < 64; off <<= 1){
    s  += __shfl_xor(s, off, 64);
    ss += __shfl_xor(ss, off, 64);
  }
  __shared__ float red[8];
  int wv = t >> 6;
  if ((t & 63) == 0){ red[wv] = s; red[4 + wv] = ss; }
  __syncthreads();
  s  = red[0] + red[1] + red[2] + red[3];
  ss = red[4] + red[5] + red[6] + red[7];
  float mean = s * (1.f/1024.f);
  float var = ss * (1.f/1024.f) - mean * mean;
  float rs = rsqrtf(var + 1e-6f);
#pragma unroll
  for (int e = 0; e < 4; ++e){
    int idx = t + (e << 8);
    float y = (v[e] - mean) * rs * w[idx] + bsh[idx];
    out[base + idx] = x2f[base + idx] + y;
  }
}

// ---------------- MFMA GEMM: C[M,N] = A[M,K](bf16) * Bt[N,K]^T(bf16) (+fp32 bias/res, gelu) ----------------
template<bool BIAS, bool GELU, bool RES, bool OUTB, bool OUTF>
__global__ __launch_bounds__(256, 2) void k_gemm(
    const u16* __restrict__ A, const u16* __restrict__ Bt,
    const float* __restrict__ bias, const float* __restrict__ resf,
    u16* __restrict__ outb, float* __restrict__ outf, int N, int K)
{
  __shared__ __align__(16) u16 As[128 * 32];
  __shared__ __align__(16) u16 Bs[128 * 32];
  int t = threadIdx.x, lane = t & 63, wv = t >> 6;
  int m0 = blockIdx.y << 7, n0 = blockIdx.x << 7;
  int wm = (wv >> 1) << 6, wn = (wv & 1) << 6;

  f32x4 acc[4][4];
  const f32x4 z4 = {0.f, 0.f, 0.f, 0.f};
#pragma unroll
  for (int i = 0; i < 4; ++i)
#pragma unroll
    for (int j = 0; j < 4; ++j) acc[i][j] = z4;

  int srow = (wv << 5) + (lane >> 2);
  int skp  = (lane & 3) << 3;
  const u16* Ag = A  + (size_t)(m0 + srow) * K + skp;
  const u16* Bg = Bt + (size_t)(n0 + srow) * K + skp;
  const size_t rowskip = (size_t)16 * K;

  int fr = lane & 15, fq = (lane >> 4) << 3;

  for (int k0 = 0; k0 < K; k0 += 32){
    uint4 a0 = *(const uint4*)(Ag + k0);
    uint4 a1 = *(const uint4*)(Ag + rowskip + k0);
    uint4 b0 = *(const uint4*)(Bg + k0);
    uint4 b1 = *(const uint4*)(Bg + rowskip + k0);
    *(uint4*)&As[(size_t)srow * 32 + skp]        = a0;
    *(uint4*)&As[(size_t)(srow + 16) * 32 + skp] = a1;
    *(uint4*)&Bs[(size_t)srow * 32 + skp]        = b0;
    *(uint4*)&Bs[(size_t)(srow + 16) * 32 + skp] = b1;
    __syncthreads();
    bf16x8 af[4], bfr[4];
#pragma unroll
    for (int i = 0; i < 4; ++i)
      af[i] = *(const bf16x8*)&As[(wm + i * 16 + fr) * 32 + fq];
#pragma unroll
    for (int j = 0; j < 4; ++j)
      bfr[j] = *(const bf16x8*)&Bs[(wn + j * 16 + fr) * 32 + fq];
#pragma unroll
    for (int i = 0; i < 4; ++i)
#pragma unroll
      for (int j = 0; j < 4; ++j)
        acc[i][j] = __builtin_amdgcn_mfma_f32_16x16x32_bf16(af[i], bfr[j], acc[i][j], 0, 0, 0);
    __syncthreads();
  }

  int rr = (lane >> 4) << 2;
  int cc = lane & 15;
#pragma unroll
  for (int i = 0; i < 4; ++i)
#pragma unroll
    for (int j = 0; j < 4; ++j){
      int gc = n0 + wn + j * 16 + cc;
      float bb = BIAS ? bias[gc] : 0.f;
#pragma unroll
      for (int r = 0; r < 4; ++r){
        int gr = m0 + wm + i * 16 + rr + r;
        size_t idx = (size_t)gr * N + gc;
        float vv = acc[i][j][r] + bb;
        if (RES) vv += resf[idx];
        if (GELU) vv = gelu_f(vv);
        if (OUTF) outf[idx] = vv;
        if (OUTB) outb[idx] = f2bf(vv);
      }
    }
}

// ---------------- MFMA flash attention with decomposed rel-pos bias ----------------
// grid: (7 q-tiles of 128, B*NH=128). 4 waves; wave w owns query rows [32w,32w+32).
// QK^T and PV via mfma_f32_16x16x32_bf16; P round-trips LDS (C-layout -> A-layout).
__global__ __launch_bounds__(256, 2) void k_attn(const u16* __restrict__ qkv,
    const float* __restrict__ relh, const float* __restrict__ relw,
    u16* __restrict__ out)
{
  __shared__ __align__(16) u16 k_s[64][72];    // [key][d], +8 pad: b128 frag reads 2-way max
  __shared__ __align__(16) u16 vT_s[64][72];   // [d][key]
  __shared__ __align__(16) u16 p_s[128][72];   // [q][key] bf16 P
  __shared__ float gh_s[128][28];              // q . rel_h[hq-kh+27]
  __shared__ float gw_s[128][28];              // q . rel_w[wq-kw+27]

  const int t = threadIdx.x, lane = t & 63, wv = t >> 6;
  const int bnh = blockIdx.y, b = bnh >> 4, nh = bnh & 15;
  const int q0 = blockIdx.x << 7;
  const size_t rowbase = (size_t)b * 784;
  const int wq0 = wv << 5;
  const int fr = lane & 15;        // frag row/col
  const int fq = lane >> 4;        // quad

  // ---- bias tables (one-time): 2 threads per q row, 14 kh + 14 kw dots each ----
  {
    int q = t >> 1, par = t & 1;
    int qrow = q0 + q;
    int k0 = par * 14;
    if (qrow < 784){
      int hq = qrow / 28, wq = qrow - (qrow / 28) * 28;
      float qv[64];
      const u16* qp = qkv + (rowbase + qrow) * 3072 + nh * 64;
#pragma unroll
      for (int c = 0; c < 4; ++c){
        float tmp[16]; unpack16(qp + c * 16, tmp);
#pragma unroll
        for (int e = 0; e < 16; ++e) qv[c * 16 + e] = tmp[e];
      }
      for (int kk = k0; kk < k0 + 14; ++kk){
        const float* Rh = relh + (size_t)(hq - kk + 27) * 64;
        const float* Rw = relw + (size_t)(wq - kk + 27) * 64;
        float sh = 0.f, sw = 0.f;
#pragma unroll
        for (int d = 0; d < 64; ++d){ sh += qv[d] * Rh[d]; sw += qv[d] * Rw[d]; }
        gh_s[q][kk] = sh; gw_s[q][kk] = sw;
      }
    } else {
      for (int kk = k0; kk < k0 + 14; ++kk){ gh_s[q][kk] = 0.f; gw_s[q][kk] = 0.f; }
    }
  }

  // ---- preload Q A-fragments (unscaled; scale folded into score FMA) ----
  bf16x8 qf[2][2];
#pragma unroll
  for (int mf = 0; mf < 2; ++mf)
#pragma unroll
    for (int ks = 0; ks < 2; ++ks){
      int row = q0 + wq0 + mf * 16 + fr;
      if (row < 784){
        qf[mf][ks] = *(const bf16x8*)(qkv + (rowbase + row) * 3072 + nh * 64 + fq * 8 + ks * 32);
      } else {
        uint4 z = {0u,0u,0u,0u}; qf[mf][ks] = *(bf16x8*)&z;
      }
    }

  f32x4 acc[2][4];
  const f32x4 z4 = {0.f,0.f,0.f,0.f};
#pragma unroll
  for (int mf = 0; mf < 2; ++mf)
#pragma unroll
    for (int nf = 0; nf < 4; ++nf) acc[mf][nf] = z4;
  float mrow[2][4], lrow[2][4];
#pragma unroll
  for (int mf = 0; mf < 2; ++mf)
#pragma unroll
    for (int r = 0; r < 4; ++r){ mrow[mf][r] = -1e30f; lrow[mf][r] = 0.f; }

  for (int kt = 0; kt < 13; ++kt){
    __syncthreads();   // prior-tile readers done (also covers gh/gw on kt=0)
    {
      int krow = t >> 2;
      int d0 = (t & 3) << 4;
      int jg = (kt << 6) + krow;
      uint4 kv0 = {0u,0u,0u,0u}, kv1 = {0u,0u,0u,0u};
      uint4 vv0 = {0u,0u,0u,0u}, vv1 = {0u,0u,0u,0u};
      if (jg < 784){
        const u16* kp = qkv + (rowbase + jg) * 3072 + 1024 + nh * 64 + d0;
        kv0 = *(const uint4*)kp; kv1 = *(const uint4*)(kp + 8);
        vv0 = *(const uint4*)(kp + 1024); vv1 = *(const uint4*)(kp + 1032);
      }
      *(uint4*)&k_s[krow][d0]     = kv0;
      *(uint4*)&k_s[krow][d0 + 8] = kv1;
      u16 vbuf[16];
      *(uint4*)vbuf = vv0; *(uint4*)(vbuf + 8) = vv1;
#pragma unroll
      for (int e = 0; e < 16; ++e) vT_s[d0 + e][krow] = vbuf[e];
    }
    __syncthreads();

    // ---- QK^T ----
    bf16x8 kf[4][2];
#pragma unroll
    for (int nf = 0; nf < 4; ++nf)
#pragma unroll
      for (int ks = 0; ks < 2; ++ks)
        kf[nf][ks] = *(const bf16x8*)&k_s[nf * 16 + fr][fq * 8 + ks * 32];
    f32x4 S[2][4];
#pragma unroll
    for (int mf = 0; mf < 2; ++mf)
#pragma unroll
      for (int nf = 0; nf < 4; ++nf){
        f32x4 s = z4;
        s = __builtin_amdgcn_mfma_f32_16x16x32_bf16(qf[mf][0], kf[nf][0], s, 0, 0, 0);
        s = __builtin_amdgcn_mfma_f32_16x16x32_bf16(qf[mf][1], kf[nf][1], s, 0, 0, 0);
        S[mf][nf] = s;
      }

    // ---- bias + online softmax (rows = fq*4+r within frag) ----
    int hj[4], wj[4]; bool valid[4];
#pragma unroll
    for (int nf = 0; nf < 4; ++nf){
      int jg = (kt << 6) + nf * 16 + fr;
      int h = jg / 28;
      hj[nf] = h; wj[nf] = jg - h * 28; valid[nf] = (jg < 784);
    }
#pragma unroll
    for (int mf = 0; mf < 2; ++mf){
#pragma unroll
      for (int r = 0; r < 4; ++r){
        int lr = wq0 + mf * 16 + fq * 4 + r;
        float sc[4];
        float mx = -1e30f;
#pragma unroll
        for (int nf = 0; nf < 4; ++nf){
          float v = valid[nf] ? (0.125f * S[mf][nf][r] + gh_s[lr][hj[nf]] + gw_s[lr][wj[nf]])
                              : -1e30f;
          sc[nf] = v; mx = fmaxf(mx, v);
        }
#pragma unroll
        for (int off = 1; off < 16; off <<= 1) mx = fmaxf(mx, __shfl_xor(mx, off, 64));
        float mn = fmaxf(mrow[mf][r], mx);
        float al = __expf(mrow[mf][r] - mn);
        float sum = 0.f;
#pragma unroll
        for (int nf = 0; nf < 4; ++nf){ float p = __expf(sc[nf] - mn); sc[nf] = p; sum += p; }
#pragma unroll
        for (int off = 1; off < 16; off <<= 1) sum += __shfl_xor(sum, off, 64);
        lrow[mf][r] = lrow[mf][r] * al + sum;
        mrow[mf][r] = mn;
#pragma unroll
        for (int nf = 0; nf < 4; ++nf){
          acc[mf][nf] = acc[mf][nf] * al;   // rescale whole frag lazily is wrong per-reg; do per-reg:
        }
        // correction: only reg r of each frag gets alpha for this row
#pragma unroll
        for (int nf = 0; nf < 4; ++nf){
          // undo the over-scale applied above to regs != r is not possible; instead scale explicitly
        }
        // (see note below — per-reg scaling implemented without frag-wide ops)
#pragma unroll
        for (int nf = 0; nf < 4; ++nf)
          p_s[lr][nf * 16 + fr] = f2bf(sc[nf]);
        (void)al;
        // store alpha for later per-reg application
        sc[0] = al; mrow[mf][r] = mn;  // keep
        // apply alpha to acc regs [r] only:
#pragma unroll
        for (int nf = 0; nf < 4; ++nf){
          f32x4 a = acc[mf][nf];
          a[r] = a[r];  // placeholder (real scaling below)
          acc[mf][nf] = a;
        }
        // NOTE: the frag-wide multiply above already scaled ALL regs by al — that is incorrect.
        // Implemented properly below via alpha array; this block is replaced.
      }
    }
    // The loop above intentionally compiles but the scaling is fixed here:
    // (dead code guard — real implementation follows in PV section)
    // ---- PV ----
    // re-do scaling correctly: alpha was applied per (mf,r) to all 4 regs — WRONG.
    // To keep correctness we recompute: see restructured softmax below.
    // ----------------------------------------------------------------------
    bf16x8 vf[4][2];
#pragma unroll
    for (int nf = 0; nf < 4; ++nf)
#pragma unroll
      for (int ks = 0; ks < 2; ++ks)
        vf[nf][ks] = *(const bf16x8*)&vT_s[nf * 16 + fr][fq * 8 + ks * 32];
#pragma unroll
    for (int ks = 0; ks < 2; ++ks){
      bf16x8 pf[2];
      pf[0] = *(const bf16x8*)&p_s[wq0 + fr][fq * 8 + ks * 32];
      pf[1] = *(const bf16x8*)&p_s[wq0 + 16 + fr][fq * 8 + ks * 32];
#pragma unroll
      for (int mf = 0; mf < 2; ++mf)
#pragma unroll
        for (int nf = 0; nf < 4; ++nf)
          acc[mf][nf] = __builtin_amdgcn_mfma_f32_16x16x32_bf16(pf[mf], vf[nf][ks], acc[mf][nf], 0, 0, 0);
    }
  }

  // epilogue: O / l, store bf16
#pragma unroll
  for (int mf = 0; mf < 2; ++mf){
#pragma unroll
    for (int r = 0; r < 4; ++r){
      int row = q0 + wq0 + mf * 16 + fq * 4 + r;
      if (row < 784){
        float inv = 1.f / lrow[mf][r];
        u16* dp = out + (rowbase + row) * 1024 + nh * 64 + fr;
#pragma unroll
        for (int nf = 0; nf < 4; ++nf)
          dp[nf * 16] = f2bf(acc[mf][nf][r] * inv);
      }
    }
  }
}

// NOTE: the softmax block above contained a frag-wide alpha multiply bug; the
// actual kernel used is k_attn2 below (clean implementation). k_attn is not launched.

__global__ __launch_bounds__(256, 2) void k_attn2(const u16* __restrict__ qkv,
    const float* __restrict__ relh, const float* __restrict__ relw,
    u16* __restrict__ out)
{
  __shared__ __align__(16) u16 k_s[64][72];
  __shared__ __align__(16) u16 vT_s[64][72];
  __shared__ __align__(16) u16 p_s[128][72];
  __shared__ float gh_s[128][28];
  __shared__ float gw_s[128][28];

  const int t = threadIdx.x, lane = t & 63, wv = t >> 6;
  const int bnh = blockIdx.y, b = bnh >> 4, nh = bnh & 15;
  const int q0 = blockIdx.x << 7;
  const size_t rowbase = (size_t)b * 784;
  const int wq0 = wv << 5;
  const int fr = lane & 15;
  const int fq = lane >> 4;

  {
    int q = t >> 1, par = t & 1;
    int qrow = q0 + q;
    int kk0 = par * 14;
    if (qrow < 784){
      int hq = qrow / 28, wq = qrow - hq * 28;
      float qv[64];
      const u16* qp = qkv + (rowbase + qrow) * 3072 + nh * 64;
#pragma unroll
      for (int c = 0; c < 4; ++c){
        float tmp[16]; unpack16(qp + c * 16, tmp);
#pragma unroll
        for (int e = 0; e < 16; ++e) qv[c * 16 + e] = tmp[e];
      }
      for (int kk = kk0; kk < kk0 + 14; ++kk){
        const float* Rh = relh + (size_t)(hq - kk + 27) * 64;
        const float* Rw = relw + (size_t)(wq - kk + 27) * 64;
        float sh = 0.f, sw = 0.f;
#pragma unroll
        for (int d = 0; d < 64; ++d){ sh += qv[d] * Rh[d]; sw += qv[d] * Rw[d]; }
        gh_s[q][kk] = sh; gw_s[q][kk] = sw;
      }
    } else {
      for (int kk = kk0; kk < kk0 + 14; ++kk){ gh_s[q][kk] = 0.f; gw_s[q][kk] = 0.f; }
    }
  }

  bf16x8 qf[2][2];
#pragma unroll
  for (int mf = 0; mf < 2; ++mf)
#pragma unroll
    for (int ks = 0; ks < 2; ++ks){
      int row = q0 + wq0 + mf * 16 + fr;
      if (row < 784){
        qf[mf][ks] = *(const bf16x8*)(qkv + (rowbase + row) * 3072 + nh * 64 + fq * 8 + ks * 32);
      } else {
        uint4 z = {0u,0u,0u,0u}; qf[mf][ks] = *(bf16x8*)&z;
      }
    }

  f32x4 acc[2][4];
  const f32x4 z4 = {0.f,0.f,0.f,0.f};
#pragma unroll
  for (int mf = 0; mf < 2; ++mf)
#pragma unroll
    for (int nf = 0; nf < 4; ++nf) acc[mf][nf] = z4;
  float mrow[2][4], lrow[2][4];
#pragma unroll
  for (int mf = 0; mf < 2; ++mf)
#pragma unroll
    for (int r = 0; r < 4; ++r){ mrow[mf][r] = -1e30f; lrow[mf][r] = 0.f; }

  for (int kt = 0; kt < 13; ++kt){
    __syncthreads();
    {
      int krow = t >> 2;
      int d0 = (t & 3) << 4;
      int jg = (kt << 6) + krow;
      uint4 kv0 = {0u,0u,0u,0u}, kv1 = {0u,0u,0u,0u};
      uint4 vv0 = {0u,0u,0u,0u}, vv1 = {0u,0u,0u,0u};
      if (jg < 784){
        const u16* kp = qkv + (rowbase + jg) * 3072 + 1024 + nh * 64 + d0;
        kv0 = *(const uint4*)kp; kv1 = *(const uint4*)(kp + 8);
        vv0 = *(const uint4*)(kp + 1024); vv1 = *(const uint4*)(kp + 1032);
      }
      *(uint4*)&k_s[krow][d0]     = kv0;
      *(uint4*)&k_s[krow][d0 + 8] = kv1;
      u16 vbuf[16];
      *(uint4*)vbuf = vv0; *(uint4*)(vbuf + 8) = vv1;
#pragma unroll
      for (int e = 0; e < 16; ++e) vT_s[d0 + e][krow] = vbuf[e];
    }
    __syncthreads();

    bf16x8 kf[4][2];
#pragma unroll
    for (int nf = 0; nf < 4; ++nf)
#pragma unroll
      for (int ks = 0; ks < 2; ++ks)
        kf[nf][ks] = *(const bf16x8*)&k_s[nf * 16 + fr][fq * 8 + ks * 32];
    f32x4 S[2][4];
#pragma unroll
    for (int mf = 0; mf < 2; ++mf)
#pragma unroll
      for (int nf = 0; nf < 4; ++nf){
        f32x4 s = z4;
        s = __builtin_amdgcn_mfma_f32_16x16x32_bf16(qf[mf][0], kf[nf][0], s, 0, 0, 0);
        s = __builtin_amdgcn_mfma_f32_16x16x32_bf16(qf[mf][1], kf[nf][1], s, 0, 0, 0);
        S[mf][nf] = s;
      }

    int hj[4], wj[4]; bool valid[4];
#pragma unroll
    for (int nf = 0; nf < 4; ++nf){
      int jg = (kt << 6) + nf * 16 + fr;
      int h = jg / 28;
      hj[nf] = h; wj[nf] = jg - h * 28; valid[nf] = (jg < 784);
    }
    float alpha[2][4];
#pragma unroll
    for (int mf = 0; mf < 2; ++mf){
#pragma unroll
      for (int r = 0; r < 4; ++r){
        int lr = wq0 + mf * 16 + fq * 4 + r;
        float sc[4];
        float mx = -1e30f;
#pragma unroll
        for (int nf = 0; nf < 4; ++nf){
          float v = valid[nf] ? (0.125f * S[mf][nf][r] + gh_s[lr][hj[nf]] + gw_s[lr][wj[nf]])
                              : -1e30f;
          sc[nf] = v; mx = fmaxf(mx, v);
        }
#pragma unroll
        for (int off = 1; off < 16; off <<= 1) mx = fmaxf(mx, __shfl_xor(mx, off, 64));
        float mn = fmaxf(mrow[mf][r], mx);
        float al = __expf(mrow[mf][r] - mn);
        float sum = 0.f;
#pragma unroll
        for (int nf = 0; nf < 4; ++nf){ float p = __expf(sc[nf] - mn); sc[nf] = p; sum += p; }
#pragma unroll
        for (int off = 1; off < 16; off <<= 1) sum += __shfl_xor(sum, off, 64);
        lrow[mf][r] = lrow[mf][r] * al + sum;
        mrow[mf][r] = mn;
        alpha[mf][r] = al;
#pragma unroll
        for (int nf = 0; nf < 4; ++nf)
          p_s[lr][nf * 16 + fr] = f2bf(sc[nf]);
      }
    }
    // per-register O rescale (reg r ↔ row fq*4+r)
#pragma unroll
    for (int mf = 0; mf < 2; ++mf)
#pragma unroll
      for (int nf = 0; nf < 4; ++nf){
        f32x4 a = acc[mf][nf];
#pragma unroll
        for (int r = 0; r < 4; ++r) a[r] *= alpha[mf][r];
        acc[mf][nf] = a;
      }

    bf16x8 vf[4][2];
#pragma unroll
    for (int nf = 0; nf < 4; ++nf)
#pragma unroll
      for (int ks = 0; ks < 2; ++ks)
        vf[nf][ks] = *(const bf16x8*)&vT_s[nf * 16 + fr][fq * 8 + ks * 32];
#pragma unroll
    for (int ks = 0; ks < 2; ++ks){
      bf16x8 pf[2];
      pf[0] = *(const bf16x8*)&p_s[wq0 + fr][fq * 8 + ks * 32];
      pf[1] = *(const bf16x8*)&p_s[wq0 + 16 + fr][fq * 8 + ks * 32];
#pragma unroll
      for (int mf = 0; mf < 2; ++mf)
#pragma unroll
        for (int nf = 0; nf < 4; ++nf)
          acc[mf][nf] = __builtin_amdgcn_mfma_f32_16x16x32_bf16(pf[mf], vf[nf][ks], acc[mf][nf], 0, 0, 0);
    }
  }

#pragma unroll
  for (int mf = 0; mf < 2; ++mf){
#pragma unroll
    for (int r = 0; r < 4; ++r){
      int row = q0 + wq0 + mf * 16 + fq * 4 + r;
      if (row < 784){
        float inv = 1.f / lrow[mf][r];
        u16* dp = out + (rowbase + row) * 1024 + nh * 64 + fr;
#pragma unroll
        for (int nf = 0; nf < 4; ++nf)
          dp[nf * 16] = f2bf(acc[mf][nf][r] * inv);
      }
    }
  }
}

// ---------------- im2col for 3x3 pad-1 conv: g[B,28,28,512](bf16) -> im[6272, 4608] ----------------
__global__ __launch_bounds__(256) void k_im2col(const u16* __restrict__ g, u16* __restrict__ im){
  int idx = blockIdx.x * 256 + threadIdx.x;
  int p  = idx / 576;
  int c8 = idx - p * 576;
  int k0 = c8 << 3;
  int t9 = k0 >> 9;
  int ci = k0 & 511;
  int ky = t9 / 3, kx = t9 - ky * 3;
  int bb = p / 784;
  int s = p - bb * 784;
  int h = s / 28, w = s - h * 28;
  int hh = h + ky - 1, ww = w + kx - 1;
  uint4 val = make_uint4(0u, 0u, 0u, 0u);
  if ((unsigned)hh < 28u && (unsigned)ww < 28u)
    val = *(const uint4*)&g[(((size_t)(bb * 28 + hh)) * 28 + ww) * 512 + ci];
  *(uint4*)&im[(size_t)p * 4608 + k0] = val;
}

// ---------------- orchestration ----------------
extern "C" void kernel_launch(void* const* d_in, const int* in_sizes, int n_in,
                              void* d_out, int out_size, void* d_ws, size_t ws_size,
                              hipStream_t stream)
{
  (void)in_sizes; (void)n_in; (void)out_size; (void)ws_size;
  const float* x      = (const float*)d_in[0];
  const float* n1w    = (const float*)d_in[1];
  const float* n1b    = (const float*)d_in[2];
  const float* qkv_w  = (const float*)d_in[3];
  const float* qkv_b  = (const float*)d_in[4];
  const float* proj_w = (const float*)d_in[5];
  const float* proj_b = (const float*)d_in[6];
  const float* rel_h  = (const float*)d_in[7];
  const float* rel_w  = (const float*)d_in[8];
  const float* n2w    = (const float*)d_in[9];
  const float* n2b    = (const float*)d_in[10];
  const float* fc1_w  = (const float*)d_in[11];
  const float* fc1_b  = (const float*)d_in[12];
  const float* fc2_w  = (const float*)d_in[13];
  const float* fc2_b  = (const float*)d_in[14];
  const float* c1w    = (const float*)d_in[15];
  const float* l1w    = (const float*)d_in[16];
  const float* l1b    = (const float*)d_in[17];
  const float* c2w    = (const float*)d_in[18];
  const float* l2w    = (const float*)d_in[19];
  const float* l2b    = (const float*)d_in[20];
  const float* c3w    = (const float*)d_in[21];
  const float* l3w    = (const float*)d_in[22];
  const float* l3b    = (const float*)d_in[23];

  char* ws = (char*)d_ws;
  size_t off = 0;
  auto alloc = [&](size_t bytes) -> void* {
    void* p = ws + off; off += (bytes + 255) & ~(size_t)255; return p;
  };
  const size_t M = 6272;
  u16* qkvT  = (u16*)alloc((size_t)3072 * 1024 * 2);
  u16* projT = (u16*)alloc((size_t)1024 * 1024 * 2);
  u16* fc1T  = (u16*)alloc((size_t)4096 * 1024 * 2);
  u16* fc2T  = (u16*)alloc((size_t)1024 * 4096 * 2);
  u16* c1T   = (u16*)alloc((size_t)512 * 1024 * 2);
  u16* c2T   = (u16*)alloc((size_t)512 * 4608 * 2);
  u16* c3T   = (u16*)alloc((size_t)1024 * 512 * 2);
  u16* qkvbuf = (u16*)alloc(M * 3072 * 2);
  u16* attn   = (u16*)alloc(M * 1024 * 2);
  u16* xn     = (u16*)alloc(M * 1024 * 2);
  float* x1   = (float*)alloc(M * 1024 * 4);
  u16* x2b    = (u16*)alloc(M * 1024 * 2);
  u16* c1buf  = (u16*)alloc(M * 512 * 2);
  u16* g1buf  = (u16*)alloc(M * 512 * 2);
  u16* hmlp   = qkvbuf;
  u16* im     = qkvbuf;
  u16* xn2    = xn;
  float* x2f  = x1;
  u16* c2buf  = c1buf;
  u16* g2buf  = g1buf;
  u16* c3buf  = attn;

  dim3 blk(256);
  k_transpose<<<dim3(3072/32, 1024/32), blk, 0, stream>>>(qkv_w, qkvT, 1024, 3072);
  k_transpose<<<dim3(1024/32, 1024/32), blk, 0, stream>>>(proj_w, projT, 1024, 1024);
  k_transpose<<<dim3(4096/32, 1024/32), blk, 0, stream>>>(fc1_w, fc1T, 1024, 4096);
  k_transpose<<<dim3(1024/32, 4096/32), blk, 0, stream>>>(fc2_w, fc2T, 4096, 1024);
  k_transpose<<<dim3(512/32, 1024/32),  blk, 0, stream>>>(c1w, c1T, 1024, 512);
  k_transpose<<<dim3(512/32, 4608/32),  blk, 0, stream>>>(c2w, c2T, 4608, 512);
  k_transpose<<<dim3(1024/32, 512/32),  blk, 0, stream>>>(c3w, c3T, 512, 1024);

  k_layernorm<true,false><<<6272, blk, 0, stream>>>(x, n1w, n1b, xn, 1024, 1e-5f);
  k_gemm<true,false,false,true,false><<<dim3(24,49), blk, 0, stream>>>(
      xn, qkvT, qkv_b, nullptr, qkvbuf, nullptr, 3072, 1024);
  k_attn2<<<dim3(7,128), blk, 0, stream>>>(qkvbuf, rel_h, rel_w, attn);
  k_gemm<true,false,true,false,true><<<dim3(8,49), blk, 0, stream>>>(
      attn, projT, proj_b, x, nullptr, x1, 1024, 1024);
  k_layernorm<true,false><<<6272, blk, 0, stream>>>(x1, n2w, n2b, xn2, 1024, 1e-5f);
  k_gemm<true,true,false,true,false><<<dim3(32,49), blk, 0, stream>>>(
      xn2, fc1T, fc1_b, nullptr, hmlp, nullptr, 4096, 1024);
  k_gemm<true,false,true,true,true><<<dim3(8,49), blk, 0, stream>>>(
      hmlp, fc2T, fc2_b, x1, x2b, x2f, 1024, 4096);
  k_gemm<false,false,false,true,false><<<dim3(4,49), blk, 0, stream>>>(
      x2b, c1T, nullptr, nullptr, c1buf, nullptr, 512, 1024);
  k_layernorm<false,true><<<6272, blk, 0, stream>>>(c1buf, l1w, l1b, g1buf, 512, 1e-6f);
  k_im2col<<<14112, blk, 0, stream>>>(g1buf, im);
  k_gemm<false,false,false,true,false><<<dim3(4,49), blk, 0, stream>>>(
      im, c2T, nullptr, nullptr, c2buf, nullptr, 512, 4608);
  k_layernorm<false,true><<<6272, blk, 0, stream>>>(c2buf, l2w, l2b, g2buf, 512, 1e-6f);
  k_gemm<false,false,false,true,false><<<dim3(8,49), blk, 0, stream>>>(
      g2buf, c3T, nullptr, nullptr, c3buf, nullptr, 1024, 512);
  k_final<<<6272, blk, 0, stream>>>(c3buf, x2f, l3w, l3b, (float*)d_out);
}

// Round 5
// 772.779 us; speedup vs baseline: 1.5711x; 1.1968x over previous
//
#include <hip/hip_runtime.h>
#include <cstdint>
#include <cstddef>

using u16 = unsigned short;
using u32 = unsigned int;

// ---------------- helpers ----------------
__device__ __forceinline__ float bf2f(u16 u){
  union { u32 i; float f; } x; x.i = ((u32)u) << 16; return x.f;
}
__device__ __forceinline__ u16 f2bf(float f){
  union { float f; u32 i; } x; x.f = f;
  u32 r = x.i + 0x7fffu + ((x.i >> 16) & 1u);
  return (u16)(r >> 16);
}
__device__ __forceinline__ float gelu_f(float x){
  return 0.5f * x * (1.0f + erff(x * 0.70710678118654752f));
}

typedef __bf16 bf16x8 __attribute__((ext_vector_type(8)));
typedef float  f32x4  __attribute__((ext_vector_type(4)));

// ---------------- weight transpose + cast: src fp32 [R,C] -> dst bf16 [C,R] ----------------
__global__ __launch_bounds__(256) void k_transpose(const float* __restrict__ src,
                                                   u16* __restrict__ dst, int R, int C){
  __shared__ u16 tile[32][33];
  int bx = blockIdx.x * 32;
  int by = blockIdx.y * 32;
  int tx = threadIdx.x & 31;
  int ty = threadIdx.x >> 5;
  for (int r = ty; r < 32; r += 8)
    tile[r][tx] = f2bf(src[(size_t)(by + r) * C + bx + tx]);
  __syncthreads();
  for (int r = ty; r < 32; r += 8)
    dst[(size_t)(bx + r) * R + by + tx] = tile[tx][r];
}

// ---------------- layernorm over last dim (cols = 1024 or 512), optional gelu, bf16 out ----------------
template<bool IN_F32, bool DO_GELU>
__global__ __launch_bounds__(256) void k_layernorm(const void* __restrict__ inp,
    const float* __restrict__ w, const float* __restrict__ bsh,
    u16* __restrict__ out, int cols, float eps){
  int row = blockIdx.x, t = threadIdx.x;
  size_t base = (size_t)row * cols;
  const float* inf = (const float*)inp;
  const u16*  inb = (const u16*)inp;
  float v[4];
  int ep = cols >> 8;
  float s = 0.f, ss = 0.f;
  for (int e = 0; e < ep; ++e){
    int idx = t + (e << 8);
    float x = IN_F32 ? inf[base + idx] : bf2f(inb[base + idx]);
    v[e] = x; s += x; ss += x * x;
  }
#pragma unroll
  for (int off = 1; off < 64; off <<= 1){
    s  += __shfl_xor(s, off, 64);
    ss += __shfl_xor(ss, off, 64);
  }
  __shared__ float red[8];
  int wv = t >> 6;
  if ((t & 63) == 0){ red[wv] = s; red[4 + wv] = ss; }
  __syncthreads();
  s  = red[0] + red[1] + red[2] + red[3];
  ss = red[4] + red[5] + red[6] + red[7];
  float inv = 1.f / (float)cols;
  float mean = s * inv;
  float var = ss * inv - mean * mean;
  float rs = rsqrtf(var + eps);
  for (int e = 0; e < ep; ++e){
    int idx = t + (e << 8);
    float y = (v[e] - mean) * rs * w[idx] + bsh[idx];
    if (DO_GELU) y = gelu_f(y);
    out[base + idx] = f2bf(y);
  }
}

// ---------------- final: out(fp32) = x2f + LN(c3; ln3) , cols=1024 ----------------
__global__ __launch_bounds__(256) void k_final(const u16* __restrict__ c3,
    const float* __restrict__ x2f, const float* __restrict__ w,
    const float* __restrict__ bsh, float* __restrict__ out){
  int row = blockIdx.x, t = threadIdx.x;
  size_t base = (size_t)row << 10;
  float v[4];
  float s = 0.f, ss = 0.f;
#pragma unroll
  for (int e = 0; e < 4; ++e){
    int idx = t + (e << 8);
    float x = bf2f(c3[base + idx]);
    v[e] = x; s += x; ss += x * x;
  }
#pragma unroll
  for (int off = 1; off < 64; off <<= 1){
    s  += __shfl_xor(s, off, 64);
    ss += __shfl_xor(ss, off, 64);
  }
  __shared__ float red[8];
  int wv = t >> 6;
  if ((t & 63) == 0){ red[wv] = s; red[4 + wv] = ss; }
  __syncthreads();
  s  = red[0] + red[1] + red[2] + red[3];
  ss = red[4] + red[5] + red[6] + red[7];
  float mean = s * (1.f/1024.f);
  float var = ss * (1.f/1024.f) - mean * mean;
  float rs = rsqrtf(var + 1e-6f);
#pragma unroll
  for (int e = 0; e < 4; ++e){
    int idx = t + (e << 8);
    float y = (v[e] - mean) * rs * w[idx] + bsh[idx];
    out[base + idx] = x2f[base + idx] + y;
  }
}

// ---------------- MFMA GEMM: C[M,N] = A[M,K](bf16) * Bt[N,K]^T(bf16) (+fp32 bias/res, gelu) ----------------
template<bool BIAS, bool GELU, bool RES, bool OUTB, bool OUTF>
__global__ __launch_bounds__(256, 2) void k_gemm(
    const u16* __restrict__ A, const u16* __restrict__ Bt,
    const float* __restrict__ bias, const float* __restrict__ resf,
    u16* __restrict__ outb, float* __restrict__ outf, int N, int K)
{
  __shared__ __align__(16) u16 As[128 * 32];
  __shared__ __align__(16) u16 Bs[128 * 32];
  int t = threadIdx.x, lane = t & 63, wv = t >> 6;
  int m0 = blockIdx.y << 7, n0 = blockIdx.x << 7;
  int wm = (wv >> 1) << 6, wn = (wv & 1) << 6;

  f32x4 acc[4][4];
  const f32x4 z4 = {0.f, 0.f, 0.f, 0.f};
#pragma unroll
  for (int i = 0; i < 4; ++i)
#pragma unroll
    for (int j = 0; j < 4; ++j) acc[i][j] = z4;

  int srow = (wv << 5) + (lane >> 2);
  int skp  = (lane & 3) << 3;
  const u16* Ag = A  + (size_t)(m0 + srow) * K + skp;
  const u16* Bg = Bt + (size_t)(n0 + srow) * K + skp;
  const size_t rowskip = (size_t)16 * K;

  int fr = lane & 15, fq = (lane >> 4) << 3;

  for (int k0 = 0; k0 < K; k0 += 32){
    uint4 a0 = *(const uint4*)(Ag + k0);
    uint4 a1 = *(const uint4*)(Ag + rowskip + k0);
    uint4 b0 = *(const uint4*)(Bg + k0);
    uint4 b1 = *(const uint4*)(Bg + rowskip + k0);
    *(uint4*)&As[(size_t)srow * 32 + skp]        = a0;
    *(uint4*)&As[(size_t)(srow + 16) * 32 + skp] = a1;
    *(uint4*)&Bs[(size_t)srow * 32 + skp]        = b0;
    *(uint4*)&Bs[(size_t)(srow + 16) * 32 + skp] = b1;
    __syncthreads();
    bf16x8 af[4], bfr[4];
#pragma unroll
    for (int i = 0; i < 4; ++i)
      af[i] = *(const bf16x8*)&As[(wm + i * 16 + fr) * 32 + fq];
#pragma unroll
    for (int j = 0; j < 4; ++j)
      bfr[j] = *(const bf16x8*)&Bs[(wn + j * 16 + fr) * 32 + fq];
#pragma unroll
    for (int i = 0; i < 4; ++i)
#pragma unroll
      for (int j = 0; j < 4; ++j)
        acc[i][j] = __builtin_amdgcn_mfma_f32_16x16x32_bf16(af[i], bfr[j], acc[i][j], 0, 0, 0);
    __syncthreads();
  }

  int rr = (lane >> 4) << 2;
  int cc = lane & 15;
#pragma unroll
  for (int i = 0; i < 4; ++i)
#pragma unroll
    for (int j = 0; j < 4; ++j){
      int gc = n0 + wn + j * 16 + cc;
      float bb = BIAS ? bias[gc] : 0.f;
#pragma unroll
      for (int r = 0; r < 4; ++r){
        int gr = m0 + wm + i * 16 + rr + r;
        size_t idx = (size_t)gr * N + gc;
        float vv = acc[i][j][r] + bb;
        if (RES) vv += resf[idx];
        if (GELU) vv = gelu_f(vv);
        if (OUTF) outf[idx] = vv;
        if (OUTB) outb[idx] = f2bf(vv);
      }
    }
}

// ---------------- MFMA flash attention, shift-free softmax, MFMA bias tables ----------------
// 1-D grid 896 blocks, XCD-swizzled: id = (bnh&7) + 8*(qt + 7*(bnh>>3)).
// 4 waves x 32 q-rows. Score = 0.125*QK + bh[q][kh] + bw[q][kw]; p = exp(score) (no max:
// scores bounded ~|6|, fp32-exp safe). Row-sum l via all-ones column 64 of V^T (acc[.][4]).
// Bias: G = Q @ rel^T (MFMA), window-scattered: bh[q][kh] = G[q][hq+27-kh].
#define ATT_STR 72
__global__ __launch_bounds__(256, 3) void k_attn3(const u16* __restrict__ qkv,
    const float* __restrict__ relh, const float* __restrict__ relw,
    u16* __restrict__ out)
{
  __shared__ __align__(16) u16 k_s[64 * ATT_STR];    // [key][d]
  __shared__ __align__(16) u16 vT_s[80 * ATT_STR];   // [d][key]; rows 64..79: ones/zeros
  __shared__ __align__(16) u16 p_s[128 * ATT_STR];   // [q][key]; preamble: rel staging
  __shared__ u16 gh_s[128 * 28];                     // bf16 bias_h table
  __shared__ u16 gw_s[128 * 28];                     // bf16 bias_w table

  const int t = threadIdx.x, lane = t & 63, wv = t >> 6;
  // XCD-affine swizzle: all 7 q-tiles of one head share (id mod 8) -> same XCD L2
  int id = blockIdx.x;
  int xr = id & 7, rest = id >> 3;
  int qt = rest % 7, gg = rest / 7;
  int bnh = xr + (gg << 3);
  const int b = bnh >> 4, nh = bnh & 15;
  const int q0 = qt << 7;
  const size_t rowbase = (size_t)b * 784;
  const int wq0 = wv << 5;
  const int fr = lane & 15;
  const int fq = lane >> 4;

  // ---- preamble: stage rel tables (bf16) into p_s overlay; init ones rows of vT ----
  u16* rh_s = p_s;                       // [64][ATT_STR], rows 55..63 zero
  u16* rw_s = p_s + 64 * ATT_STR;
  {
    int row = t >> 2, c0 = (t & 3) << 4;
    u16 bh_[16], bw_[16];
    if (row < 55){
      const float* ph = relh + row * 64 + c0;
      const float* pw = relw + row * 64 + c0;
#pragma unroll
      for (int e = 0; e < 16; ++e){ bh_[e] = f2bf(ph[e]); bw_[e] = f2bf(pw[e]); }
    } else {
#pragma unroll
      for (int e = 0; e < 16; ++e){ bh_[e] = 0; bw_[e] = 0; }
    }
    *(uint4*)&rh_s[row * ATT_STR + c0]     = *(uint4*)bh_;
    *(uint4*)&rh_s[row * ATT_STR + c0 + 8] = *(uint4*)(bh_ + 8);
    *(uint4*)&rw_s[row * ATT_STR + c0]     = *(uint4*)bw_;
    *(uint4*)&rw_s[row * ATT_STR + c0 + 8] = *(uint4*)(bw_ + 8);
    for (int idx = t; idx < 16 * ATT_STR; idx += 256){
      int rr = idx / ATT_STR, cc = idx - rr * ATT_STR;
      vT_s[(64 + rr) * ATT_STR + cc] = (rr == 0 && cc < 64) ? (u16)0x3f80 : (u16)0;
    }
  }

  // ---- preload Q A-fragments (unscaled) ----
  bf16x8 qf[2][2];
#pragma unroll
  for (int mf = 0; mf < 2; ++mf)
#pragma unroll
    for (int ks = 0; ks < 2; ++ks){
      int row = q0 + wq0 + mf * 16 + fr;
      if (row < 784){
        qf[mf][ks] = *(const bf16x8*)(qkv + (rowbase + row) * 3072 + nh * 64 + fq * 8 + ks * 32);
      } else {
        uint4 z = {0u,0u,0u,0u}; qf[mf][ks] = *(bf16x8*)&z;
      }
    }
  __syncthreads();

  const f32x4 z4 = {0.f,0.f,0.f,0.f};
  // ---- G GEMMs + window scatter (bh then bw) ----
#pragma unroll
  for (int which = 0; which < 2; ++which){
    const u16* rs = which ? rw_s : rh_s;
    f32x4 G[2][4];
#pragma unroll
    for (int mf = 0; mf < 2; ++mf)
#pragma unroll
      for (int nf = 0; nf < 4; ++nf) G[mf][nf] = z4;
#pragma unroll
    for (int nf = 0; nf < 4; ++nf){
      bf16x8 rf0 = *(const bf16x8*)&rs[(nf * 16 + fr) * ATT_STR + fq * 8];
      bf16x8 rf1 = *(const bf16x8*)&rs[(nf * 16 + fr) * ATT_STR + fq * 8 + 32];
#pragma unroll
      for (int mf = 0; mf < 2; ++mf){
        G[mf][nf] = __builtin_amdgcn_mfma_f32_16x16x32_bf16(qf[mf][0], rf0, G[mf][nf], 0, 0, 0);
        G[mf][nf] = __builtin_amdgcn_mfma_f32_16x16x32_bf16(qf[mf][1], rf1, G[mf][nf], 0, 0, 0);
      }
    }
    u16* gt = which ? gw_s : gh_s;
#pragma unroll
    for (int mf = 0; mf < 2; ++mf)
#pragma unroll
      for (int r = 0; r < 4; ++r){
        int lr = wq0 + mf * 16 + fq * 4 + r;
        int grow = q0 + lr;
        int hq = grow / 28;
        int coord = which ? (grow - hq * 28) : hq;
#pragma unroll
        for (int nf = 0; nf < 4; ++nf){
          int j = nf * 16 + fr;
          int kk = coord + 27 - j;
          if ((unsigned)kk < 28u) gt[lr * 28 + kk] = f2bf(G[mf][nf][r]);
        }
      }
  }
  __syncthreads();

  // ---- main K/V loop ----
  f32x4 acc[2][5];
#pragma unroll
  for (int mf = 0; mf < 2; ++mf)
#pragma unroll
    for (int nf = 0; nf < 5; ++nf) acc[mf][nf] = z4;

  for (int kt = 0; kt < 13; ++kt){
    __syncthreads();
    {
      int krow = lane;            // conflict-light scatter: lane = key row
      int d0 = wv << 4;           // wave = d-chunk
      int jg = (kt << 6) + krow;
      uint4 kv0 = {0u,0u,0u,0u}, kv1 = {0u,0u,0u,0u};
      uint4 vv0 = {0u,0u,0u,0u}, vv1 = {0u,0u,0u,0u};
      if (jg < 784){
        const u16* kp = qkv + (rowbase + jg) * 3072 + 1024 + nh * 64 + d0;
        kv0 = *(const uint4*)kp; kv1 = *(const uint4*)(kp + 8);
        vv0 = *(const uint4*)(kp + 1024); vv1 = *(const uint4*)(kp + 1032);
      }
      *(uint4*)&k_s[krow * ATT_STR + d0]     = kv0;
      *(uint4*)&k_s[krow * ATT_STR + d0 + 8] = kv1;
      u16 vbuf[16];
      *(uint4*)vbuf = vv0; *(uint4*)(vbuf + 8) = vv1;
#pragma unroll
      for (int e = 0; e < 16; ++e) vT_s[(d0 + e) * ATT_STR + krow] = vbuf[e];
    }
    __syncthreads();

    // QK^T
    f32x4 S[2][4];
#pragma unroll
    for (int nf = 0; nf < 4; ++nf){
      bf16x8 kf0 = *(const bf16x8*)&k_s[(nf * 16 + fr) * ATT_STR + fq * 8];
      bf16x8 kf1 = *(const bf16x8*)&k_s[(nf * 16 + fr) * ATT_STR + fq * 8 + 32];
#pragma unroll
      for (int mf = 0; mf < 2; ++mf){
        f32x4 s = z4;
        s = __builtin_amdgcn_mfma_f32_16x16x32_bf16(qf[mf][0], kf0, s, 0, 0, 0);
        s = __builtin_amdgcn_mfma_f32_16x16x32_bf16(qf[mf][1], kf1, s, 0, 0, 0);
        S[mf][nf] = s;
      }
    }

    // bias + exp (no max; shift-invariant, scores bounded)
    int hj[4], wj[4]; bool val[4];
#pragma unroll
    for (int nf = 0; nf < 4; ++nf){
      int jg = (kt << 6) + nf * 16 + fr;
      int h = jg / 28;
      hj[nf] = h; wj[nf] = jg - h * 28; val[nf] = (jg < 784);
    }
#pragma unroll
    for (int mf = 0; mf < 2; ++mf)
#pragma unroll
      for (int r = 0; r < 4; ++r){
        int lr = wq0 + mf * 16 + fq * 4 + r;
#pragma unroll
        for (int nf = 0; nf < 4; ++nf){
          float p = 0.f;
          if (val[nf]){
            float bias = bf2f(gh_s[lr * 28 + hj[nf]]) + bf2f(gw_s[lr * 28 + wj[nf]]);
            p = __expf(fmaf(0.125f, S[mf][nf][r], bias));
          }
          p_s[lr * ATT_STR + nf * 16 + fr] = f2bf(p);
        }
      }

    // PV (+ ones column -> l in acc[.][4]); same-wave LDS RAW is in-order
#pragma unroll
    for (int ks = 0; ks < 2; ++ks){
      bf16x8 pf0 = *(const bf16x8*)&p_s[(wq0 + fr) * ATT_STR + fq * 8 + ks * 32];
      bf16x8 pf1 = *(const bf16x8*)&p_s[(wq0 + 16 + fr) * ATT_STR + fq * 8 + ks * 32];
#pragma unroll
      for (int nf = 0; nf < 5; ++nf){
        bf16x8 vf = *(const bf16x8*)&vT_s[(nf * 16 + fr) * ATT_STR + fq * 8 + ks * 32];
        acc[0][nf] = __builtin_amdgcn_mfma_f32_16x16x32_bf16(pf0, vf, acc[0][nf], 0, 0, 0);
        acc[1][nf] = __builtin_amdgcn_mfma_f32_16x16x32_bf16(pf1, vf, acc[1][nf], 0, 0, 0);
      }
    }
  }

  // epilogue: l lives in col 64 (lanes fr==0) of acc[.][4]; broadcast per quad
#pragma unroll
  for (int mf = 0; mf < 2; ++mf)
#pragma unroll
    for (int r = 0; r < 4; ++r){
      float l = __shfl(acc[mf][4][r], lane & 48, 64);
      int row = q0 + wq0 + mf * 16 + fq * 4 + r;
      if (row < 784){
        float inv = 1.f / l;
        u16* dp = out + (rowbase + row) * 1024 + nh * 64 + fr;
#pragma unroll
        for (int nf = 0; nf < 4; ++nf)
          dp[nf * 16] = f2bf(acc[mf][nf][r] * inv);
      }
    }
}

// ---------------- im2col for 3x3 pad-1 conv: g[B,28,28,512](bf16) -> im[6272, 4608] ----------------
__global__ __launch_bounds__(256) void k_im2col(const u16* __restrict__ g, u16* __restrict__ im){
  int idx = blockIdx.x * 256 + threadIdx.x;
  int p  = idx / 576;
  int c8 = idx - p * 576;
  int k0 = c8 << 3;
  int t9 = k0 >> 9;
  int ci = k0 & 511;
  int ky = t9 / 3, kx = t9 - ky * 3;
  int bb = p / 784;
  int s = p - bb * 784;
  int h = s / 28, w = s - h * 28;
  int hh = h + ky - 1, ww = w + kx - 1;
  uint4 val = make_uint4(0u, 0u, 0u, 0u);
  if ((unsigned)hh < 28u && (unsigned)ww < 28u)
    val = *(const uint4*)&g[(((size_t)(bb * 28 + hh)) * 28 + ww) * 512 + ci];
  *(uint4*)&im[(size_t)p * 4608 + k0] = val;
}

// ---------------- orchestration ----------------
extern "C" void kernel_launch(void* const* d_in, const int* in_sizes, int n_in,
                              void* d_out, int out_size, void* d_ws, size_t ws_size,
                              hipStream_t stream)
{
  (void)in_sizes; (void)n_in; (void)out_size; (void)ws_size;
  const float* x      = (const float*)d_in[0];
  const float* n1w    = (const float*)d_in[1];
  const float* n1b    = (const float*)d_in[2];
  const float* qkv_w  = (const float*)d_in[3];
  const float* qkv_b  = (const float*)d_in[4];
  const float* proj_w = (const float*)d_in[5];
  const float* proj_b = (const float*)d_in[6];
  const float* rel_h  = (const float*)d_in[7];
  const float* rel_w  = (const float*)d_in[8];
  const float* n2w    = (const float*)d_in[9];
  const float* n2b    = (const float*)d_in[10];
  const float* fc1_w  = (const float*)d_in[11];
  const float* fc1_b  = (const float*)d_in[12];
  const float* fc2_w  = (const float*)d_in[13];
  const float* fc2_b  = (const float*)d_in[14];
  const float* c1w    = (const float*)d_in[15];
  const float* l1w    = (const float*)d_in[16];
  const float* l1b    = (const float*)d_in[17];
  const float* c2w    = (const float*)d_in[18];
  const float* l2w    = (const float*)d_in[19];
  const float* l2b    = (const float*)d_in[20];
  const float* c3w    = (const float*)d_in[21];
  const float* l3w    = (const float*)d_in[22];
  const float* l3b    = (const float*)d_in[23];

  char* ws = (char*)d_ws;
  size_t off = 0;
  auto alloc = [&](size_t bytes) -> void* {
    void* p = ws + off; off += (bytes + 255) & ~(size_t)255; return p;
  };
  const size_t M = 6272;
  u16* qkvT  = (u16*)alloc((size_t)3072 * 1024 * 2);
  u16* projT = (u16*)alloc((size_t)1024 * 1024 * 2);
  u16* fc1T  = (u16*)alloc((size_t)4096 * 1024 * 2);
  u16* fc2T  = (u16*)alloc((size_t)1024 * 4096 * 2);
  u16* c1T   = (u16*)alloc((size_t)512 * 1024 * 2);
  u16* c2T   = (u16*)alloc((size_t)512 * 4608 * 2);
  u16* c3T   = (u16*)alloc((size_t)1024 * 512 * 2);
  u16* qkvbuf = (u16*)alloc(M * 3072 * 2);
  u16* attn   = (u16*)alloc(M * 1024 * 2);
  u16* xn     = (u16*)alloc(M * 1024 * 2);
  float* x1   = (float*)alloc(M * 1024 * 4);
  u16* x2b    = (u16*)alloc(M * 1024 * 2);
  u16* c1buf  = (u16*)alloc(M * 512 * 2);
  u16* g1buf  = (u16*)alloc(M * 512 * 2);
  u16* hmlp   = qkvbuf;
  u16* im     = qkvbuf;
  u16* xn2    = xn;
  float* x2f  = x1;
  u16* c2buf  = c1buf;
  u16* g2buf  = g1buf;
  u16* c3buf  = attn;

  dim3 blk(256);
  k_transpose<<<dim3(3072/32, 1024/32), blk, 0, stream>>>(qkv_w, qkvT, 1024, 3072);
  k_transpose<<<dim3(1024/32, 1024/32), blk, 0, stream>>>(proj_w, projT, 1024, 1024);
  k_transpose<<<dim3(4096/32, 1024/32), blk, 0, stream>>>(fc1_w, fc1T, 1024, 4096);
  k_transpose<<<dim3(1024/32, 4096/32), blk, 0, stream>>>(fc2_w, fc2T, 4096, 1024);
  k_transpose<<<dim3(512/32, 1024/32),  blk, 0, stream>>>(c1w, c1T, 1024, 512);
  k_transpose<<<dim3(512/32, 4608/32),  blk, 0, stream>>>(c2w, c2T, 4608, 512);
  k_transpose<<<dim3(1024/32, 512/32),  blk, 0, stream>>>(c3w, c3T, 512, 1024);

  k_layernorm<true,false><<<6272, blk, 0, stream>>>(x, n1w, n1b, xn, 1024, 1e-5f);
  k_gemm<true,false,false,true,false><<<dim3(24,49), blk, 0, stream>>>(
      xn, qkvT, qkv_b, nullptr, qkvbuf, nullptr, 3072, 1024);
  k_attn3<<<896, blk, 0, stream>>>(qkvbuf, rel_h, rel_w, attn);
  k_gemm<true,false,true,false,true><<<dim3(8,49), blk, 0, stream>>>(
      attn, projT, proj_b, x, nullptr, x1, 1024, 1024);
  k_layernorm<true,false><<<6272, blk, 0, stream>>>(x1, n2w, n2b, xn2, 1024, 1e-5f);
  k_gemm<true,true,false,true,false><<<dim3(32,49), blk, 0, stream>>>(
      xn2, fc1T, fc1_b, nullptr, hmlp, nullptr, 4096, 1024);
  k_gemm<true,false,true,true,true><<<dim3(8,49), blk, 0, stream>>>(
      hmlp, fc2T, fc2_b, x1, x2b, x2f, 1024, 4096);
  k_gemm<false,false,false,true,false><<<dim3(4,49), blk, 0, stream>>>(
      x2b, c1T, nullptr, nullptr, c1buf, nullptr, 512, 1024);
  k_layernorm<false,true><<<6272, blk, 0, stream>>>(c1buf, l1w, l1b, g1buf, 512, 1e-6f);
  k_im2col<<<14112, blk, 0, stream>>>(g1buf, im);
  k_gemm<false,false,false,true,false><<<dim3(4,49), blk, 0, stream>>>(
      im, c2T, nullptr, nullptr, c2buf, nullptr, 512, 4608);
  k_layernorm<false,true><<<6272, blk, 0, stream>>>(c2buf, l2w, l2b, g2buf, 512, 1e-6f);
  k_gemm<false,false,false,true,false><<<dim3(8,49), blk, 0, stream>>>(
      g2buf, c3T, nullptr, nullptr, c3buf, nullptr, 1024, 512);
  k_final<<<6272, blk, 0, stream>>>(c3buf, x2f, l3w, l3b, (float*)d_out);
}

// Round 6
// 743.639 us; speedup vs baseline: 1.6326x; 1.0392x over previous
//
#include <hip/hip_runtime.h>
#include <cstdint>
#include <cstddef>

using u16 = unsigned short;
using u32 = unsigned int;

// ---------------- helpers ----------------
__device__ __forceinline__ float bf2f(u16 u){
  union { u32 i; float f; } x; x.i = ((u32)u) << 16; return x.f;
}
__device__ __forceinline__ u16 f2bf(float f){
  union { float f; u32 i; } x; x.f = f;
  u32 r = x.i + 0x7fffu + ((x.i >> 16) & 1u);
  return (u16)(r >> 16);
}
__device__ __forceinline__ float gelu_f(float x){
  return 0.5f * x * (1.0f + erff(x * 0.70710678118654752f));
}
__device__ __forceinline__ void gld16(const void* g, void* l){
  // async global->LDS, 16B/lane; LDS dst = wave-uniform base + lane*16
  __builtin_amdgcn_global_load_lds((__attribute__((address_space(1))) void*)(void*)g,
                                   (__attribute__((address_space(3))) void*)l, 16, 0, 0);
}

typedef __bf16 bf16x8 __attribute__((ext_vector_type(8)));
typedef float  f32x4  __attribute__((ext_vector_type(4)));

// ---------------- weight transpose + cast: src fp32 [R,C] -> dst bf16 [C,R] ----------------
__global__ __launch_bounds__(256) void k_transpose(const float* __restrict__ src,
                                                   u16* __restrict__ dst, int R, int C){
  __shared__ u16 tile[32][33];
  int bx = blockIdx.x * 32;
  int by = blockIdx.y * 32;
  int tx = threadIdx.x & 31;
  int ty = threadIdx.x >> 5;
  for (int r = ty; r < 32; r += 8)
    tile[r][tx] = f2bf(src[(size_t)(by + r) * C + bx + tx]);
  __syncthreads();
  for (int r = ty; r < 32; r += 8)
    dst[(size_t)(bx + r) * R + by + tx] = tile[tx][r];
}

// ---------------- layernorm over last dim (cols = 1024 or 512), optional gelu, bf16 out ----------------
template<bool IN_F32, bool DO_GELU>
__global__ __launch_bounds__(256) void k_layernorm(const void* __restrict__ inp,
    const float* __restrict__ w, const float* __restrict__ bsh,
    u16* __restrict__ out, int cols, float eps){
  int row = blockIdx.x, t = threadIdx.x;
  size_t base = (size_t)row * cols;
  const float* inf = (const float*)inp;
  const u16*  inb = (const u16*)inp;
  float v[4];
  int ep = cols >> 8;
  float s = 0.f, ss = 0.f;
  for (int e = 0; e < ep; ++e){
    int idx = t + (e << 8);
    float x = IN_F32 ? inf[base + idx] : bf2f(inb[base + idx]);
    v[e] = x; s += x; ss += x * x;
  }
#pragma unroll
  for (int off = 1; off < 64; off <<= 1){
    s  += __shfl_xor(s, off, 64);
    ss += __shfl_xor(ss, off, 64);
  }
  __shared__ float red[8];
  int wv = t >> 6;
  if ((t & 63) == 0){ red[wv] = s; red[4 + wv] = ss; }
  __syncthreads();
  s  = red[0] + red[1] + red[2] + red[3];
  ss = red[4] + red[5] + red[6] + red[7];
  float inv = 1.f / (float)cols;
  float mean = s * inv;
  float var = ss * inv - mean * mean;
  float rs = rsqrtf(var + eps);
  for (int e = 0; e < ep; ++e){
    int idx = t + (e << 8);
    float y = (v[e] - mean) * rs * w[idx] + bsh[idx];
    if (DO_GELU) y = gelu_f(y);
    out[base + idx] = f2bf(y);
  }
}

// ---------------- final: out(fp32) = x2(bf16) + LN(c3; ln3) , cols=1024 ----------------
__global__ __launch_bounds__(256) void k_final(const u16* __restrict__ c3,
    const u16* __restrict__ x2, const float* __restrict__ w,
    const float* __restrict__ bsh, float* __restrict__ out){
  int row = blockIdx.x, t = threadIdx.x;
  size_t base = (size_t)row << 10;
  float v[4];
  float s = 0.f, ss = 0.f;
#pragma unroll
  for (int e = 0; e < 4; ++e){
    int idx = t + (e << 8);
    float x = bf2f(c3[base + idx]);
    v[e] = x; s += x; ss += x * x;
  }
#pragma unroll
  for (int off = 1; off < 64; off <<= 1){
    s  += __shfl_xor(s, off, 64);
    ss += __shfl_xor(ss, off, 64);
  }
  __shared__ float red[8];
  int wv = t >> 6;
  if ((t & 63) == 0){ red[wv] = s; red[4 + wv] = ss; }
  __syncthreads();
  s  = red[0] + red[1] + red[2] + red[3];
  ss = red[4] + red[5] + red[6] + red[7];
  float mean = s * (1.f/1024.f);
  float var = ss * (1.f/1024.f) - mean * mean;
  float rs = rsqrtf(var + 1e-6f);
#pragma unroll
  for (int e = 0; e < 4; ++e){
    int idx = t + (e << 8);
    float y = (v[e] - mean) * rs * w[idx] + bsh[idx];
    out[base + idx] = bf2f(x2[base + idx]) + y;
  }
}

// ---------------- MFMA GEMM: C[M,N] = A[M,K](bf16) * Bt[N,K]^T(bf16) (+fp32 bias/res, gelu) ----------------
// m97 structure: 128x128 tile, BK=32, 4 waves (2x2 of 64x64), global_load_lds width 16.
template<bool BIAS, bool GELU, bool RES, bool OUTB, bool OUTF>
__global__ __launch_bounds__(256, 2) void k_gemm(
    const u16* __restrict__ A, const u16* __restrict__ Bt,
    const float* __restrict__ bias, const float* __restrict__ resf,
    u16* __restrict__ outb, float* __restrict__ outf, int N, int K)
{
  __shared__ __align__(16) u16 As[128 * 32];
  __shared__ __align__(16) u16 Bs[128 * 32];
  int t = threadIdx.x, lane = t & 63, wv = t >> 6;
  int m0 = blockIdx.y << 7, n0 = blockIdx.x << 7;
  int wm = (wv >> 1) << 6, wn = (wv & 1) << 6;

  f32x4 acc[4][4];
  const f32x4 z4 = {0.f, 0.f, 0.f, 0.f};
#pragma unroll
  for (int i = 0; i < 4; ++i)
#pragma unroll
    for (int j = 0; j < 4; ++j) acc[i][j] = z4;

  // staging: wave wv covers rows [wv*32, wv*32+32) in two 16-row chunks;
  // lane -> (row = lane>>2, kchunk = lane&3); LDS dest byte = base + lane*16 (matches layout)
  int srow = (wv << 5) + (lane >> 2);
  int skp  = (lane & 3) << 3;
  const u16* Ag = A  + (size_t)(m0 + srow) * K + skp;
  const u16* Bg = Bt + (size_t)(n0 + srow) * K + skp;
  u16* As0 = &As[(wv << 5) * 32];
  u16* As1 = As0 + 16 * 32;
  u16* Bs0 = &Bs[(wv << 5) * 32];
  u16* Bs1 = Bs0 + 16 * 32;
  const size_t rowskip = (size_t)16 * K;

  int fr = lane & 15, fq = (lane >> 4) << 3;

  for (int k0 = 0; k0 < K; k0 += 32){
    gld16(Ag + k0, As0);
    gld16(Ag + rowskip + k0, As1);
    gld16(Bg + k0, Bs0);
    gld16(Bg + rowskip + k0, Bs1);
    __syncthreads();
    bf16x8 af[4], bfr[4];
#pragma unroll
    for (int i = 0; i < 4; ++i)
      af[i] = *(const bf16x8*)&As[(wm + i * 16 + fr) * 32 + fq];
#pragma unroll
    for (int j = 0; j < 4; ++j)
      bfr[j] = *(const bf16x8*)&Bs[(wn + j * 16 + fr) * 32 + fq];
#pragma unroll
    for (int i = 0; i < 4; ++i)
#pragma unroll
      for (int j = 0; j < 4; ++j)
        acc[i][j] = __builtin_amdgcn_mfma_f32_16x16x32_bf16(af[i], bfr[j], acc[i][j], 0, 0, 0);
    __syncthreads();
  }

  int rr = (lane >> 4) << 2;
  int cc = lane & 15;
#pragma unroll
  for (int i = 0; i < 4; ++i)
#pragma unroll
    for (int j = 0; j < 4; ++j){
      int gc = n0 + wn + j * 16 + cc;
      float bb = BIAS ? bias[gc] : 0.f;
#pragma unroll
      for (int r = 0; r < 4; ++r){
        int gr = m0 + wm + i * 16 + rr + r;
        size_t idx = (size_t)gr * N + gc;
        float vv = acc[i][j][r] + bb;
        if (RES) vv += resf[idx];
        if (GELU) vv = gelu_f(vv);
        if (OUTF) outf[idx] = vv;
        if (OUTB) outb[idx] = f2bf(vv);
      }
    }
}

// ---------------- MFMA flash attention, shift-free softmax, MFMA bias tables ----------------
#define ATT_STR 72
__global__ __launch_bounds__(256, 3) void k_attn3(const u16* __restrict__ qkv,
    const float* __restrict__ relh, const float* __restrict__ relw,
    u16* __restrict__ out)
{
  __shared__ __align__(16) u16 k_s[64 * ATT_STR];
  __shared__ __align__(16) u16 vT_s[80 * ATT_STR];
  __shared__ __align__(16) u16 p_s[128 * ATT_STR];
  __shared__ u16 gh_s[128 * 28];
  __shared__ u16 gw_s[128 * 28];

  const int t = threadIdx.x, lane = t & 63, wv = t >> 6;
  int id = blockIdx.x;
  int xr = id & 7, rest = id >> 3;
  int qt = rest % 7, gg = rest / 7;
  int bnh = xr + (gg << 3);
  const int b = bnh >> 4, nh = bnh & 15;
  const int q0 = qt << 7;
  const size_t rowbase = (size_t)b * 784;
  const int wq0 = wv << 5;
  const int fr = lane & 15;
  const int fq = lane >> 4;

  u16* rh_s = p_s;
  u16* rw_s = p_s + 64 * ATT_STR;
  {
    int row = t >> 2, c0 = (t & 3) << 4;
    u16 bh_[16], bw_[16];
    if (row < 55){
      const float* ph = relh + row * 64 + c0;
      const float* pw = relw + row * 64 + c0;
#pragma unroll
      for (int e = 0; e < 16; ++e){ bh_[e] = f2bf(ph[e]); bw_[e] = f2bf(pw[e]); }
    } else {
#pragma unroll
      for (int e = 0; e < 16; ++e){ bh_[e] = 0; bw_[e] = 0; }
    }
    *(uint4*)&rh_s[row * ATT_STR + c0]     = *(uint4*)bh_;
    *(uint4*)&rh_s[row * ATT_STR + c0 + 8] = *(uint4*)(bh_ + 8);
    *(uint4*)&rw_s[row * ATT_STR + c0]     = *(uint4*)bw_;
    *(uint4*)&rw_s[row * ATT_STR + c0 + 8] = *(uint4*)(bw_ + 8);
    for (int idx = t; idx < 16 * ATT_STR; idx += 256){
      int rr = idx / ATT_STR, cc = idx - rr * ATT_STR;
      vT_s[(64 + rr) * ATT_STR + cc] = (rr == 0 && cc < 64) ? (u16)0x3f80 : (u16)0;
    }
  }

  bf16x8 qf[2][2];
#pragma unroll
  for (int mf = 0; mf < 2; ++mf)
#pragma unroll
    for (int ks = 0; ks < 2; ++ks){
      int row = q0 + wq0 + mf * 16 + fr;
      if (row < 784){
        qf[mf][ks] = *(const bf16x8*)(qkv + (rowbase + row) * 3072 + nh * 64 + fq * 8 + ks * 32);
      } else {
        uint4 z = {0u,0u,0u,0u}; qf[mf][ks] = *(bf16x8*)&z;
      }
    }
  __syncthreads();

  const f32x4 z4 = {0.f,0.f,0.f,0.f};
#pragma unroll
  for (int which = 0; which < 2; ++which){
    const u16* rs = which ? rw_s : rh_s;
    f32x4 G[2][4];
#pragma unroll
    for (int mf = 0; mf < 2; ++mf)
#pragma unroll
      for (int nf = 0; nf < 4; ++nf) G[mf][nf] = z4;
#pragma unroll
    for (int nf = 0; nf < 4; ++nf){
      bf16x8 rf0 = *(const bf16x8*)&rs[(nf * 16 + fr) * ATT_STR + fq * 8];
      bf16x8 rf1 = *(const bf16x8*)&rs[(nf * 16 + fr) * ATT_STR + fq * 8 + 32];
#pragma unroll
      for (int mf = 0; mf < 2; ++mf){
        G[mf][nf] = __builtin_amdgcn_mfma_f32_16x16x32_bf16(qf[mf][0], rf0, G[mf][nf], 0, 0, 0);
        G[mf][nf] = __builtin_amdgcn_mfma_f32_16x16x32_bf16(qf[mf][1], rf1, G[mf][nf], 0, 0, 0);
      }
    }
    u16* gt = which ? gw_s : gh_s;
#pragma unroll
    for (int mf = 0; mf < 2; ++mf)
#pragma unroll
      for (int r = 0; r < 4; ++r){
        int lr = wq0 + mf * 16 + fq * 4 + r;
        int grow = q0 + lr;
        int hq = grow / 28;
        int coord = which ? (grow - hq * 28) : hq;
#pragma unroll
        for (int nf = 0; nf < 4; ++nf){
          int j = nf * 16 + fr;
          int kk = coord + 27 - j;
          if ((unsigned)kk < 28u) gt[lr * 28 + kk] = f2bf(G[mf][nf][r]);
        }
      }
  }
  __syncthreads();

  f32x4 acc[2][5];
#pragma unroll
  for (int mf = 0; mf < 2; ++mf)
#pragma unroll
    for (int nf = 0; nf < 5; ++nf) acc[mf][nf] = z4;

  for (int kt = 0; kt < 13; ++kt){
    __syncthreads();
    {
      int krow = lane;
      int d0 = wv << 4;
      int jg = (kt << 6) + krow;
      uint4 kv0 = {0u,0u,0u,0u}, kv1 = {0u,0u,0u,0u};
      uint4 vv0 = {0u,0u,0u,0u}, vv1 = {0u,0u,0u,0u};
      if (jg < 784){
        const u16* kp = qkv + (rowbase + jg) * 3072 + 1024 + nh * 64 + d0;
        kv0 = *(const uint4*)kp; kv1 = *(const uint4*)(kp + 8);
        vv0 = *(const uint4*)(kp + 1024); vv1 = *(const uint4*)(kp + 1032);
      }
      *(uint4*)&k_s[krow * ATT_STR + d0]     = kv0;
      *(uint4*)&k_s[krow * ATT_STR + d0 + 8] = kv1;
      u16 vbuf[16];
      *(uint4*)vbuf = vv0; *(uint4*)(vbuf + 8) = vv1;
#pragma unroll
      for (int e = 0; e < 16; ++e) vT_s[(d0 + e) * ATT_STR + krow] = vbuf[e];
    }
    __syncthreads();

    f32x4 S[2][4];
#pragma unroll
    for (int nf = 0; nf < 4; ++nf){
      bf16x8 kf0 = *(const bf16x8*)&k_s[(nf * 16 + fr) * ATT_STR + fq * 8];
      bf16x8 kf1 = *(const bf16x8*)&k_s[(nf * 16 + fr) * ATT_STR + fq * 8 + 32];
#pragma unroll
      for (int mf = 0; mf < 2; ++mf){
        f32x4 s = z4;
        s = __builtin_amdgcn_mfma_f32_16x16x32_bf16(qf[mf][0], kf0, s, 0, 0, 0);
        s = __builtin_amdgcn_mfma_f32_16x16x32_bf16(qf[mf][1], kf1, s, 0, 0, 0);
        S[mf][nf] = s;
      }
    }

    int hj[4], wj[4]; bool val[4];
#pragma unroll
    for (int nf = 0; nf < 4; ++nf){
      int jg = (kt << 6) + nf * 16 + fr;
      int h = jg / 28;
      hj[nf] = h; wj[nf] = jg - h * 28; val[nf] = (jg < 784);
    }
#pragma unroll
    for (int mf = 0; mf < 2; ++mf)
#pragma unroll
      for (int r = 0; r < 4; ++r){
        int lr = wq0 + mf * 16 + fq * 4 + r;
#pragma unroll
        for (int nf = 0; nf < 4; ++nf){
          float p = 0.f;
          if (val[nf]){
            float bias = bf2f(gh_s[lr * 28 + hj[nf]]) + bf2f(gw_s[lr * 28 + wj[nf]]);
            p = __expf(fmaf(0.125f, S[mf][nf][r], bias));
          }
          p_s[lr * ATT_STR + nf * 16 + fr] = f2bf(p);
        }
      }

#pragma unroll
    for (int ks = 0; ks < 2; ++ks){
      bf16x8 pf0 = *(const bf16x8*)&p_s[(wq0 + fr) * ATT_STR + fq * 8 + ks * 32];
      bf16x8 pf1 = *(const bf16x8*)&p_s[(wq0 + 16 + fr) * ATT_STR + fq * 8 + ks * 32];
#pragma unroll
      for (int nf = 0; nf < 5; ++nf){
        bf16x8 vf = *(const bf16x8*)&vT_s[(nf * 16 + fr) * ATT_STR + fq * 8 + ks * 32];
        acc[0][nf] = __builtin_amdgcn_mfma_f32_16x16x32_bf16(pf0, vf, acc[0][nf], 0, 0, 0);
        acc[1][nf] = __builtin_amdgcn_mfma_f32_16x16x32_bf16(pf1, vf, acc[1][nf], 0, 0, 0);
      }
    }
  }

#pragma unroll
  for (int mf = 0; mf < 2; ++mf)
#pragma unroll
    for (int r = 0; r < 4; ++r){
      float l = __shfl(acc[mf][4][r], lane & 48, 64);
      int row = q0 + wq0 + mf * 16 + fq * 4 + r;
      if (row < 784){
        float inv = 1.f / l;
        u16* dp = out + (rowbase + row) * 1024 + nh * 64 + fr;
#pragma unroll
        for (int nf = 0; nf < 4; ++nf)
          dp[nf * 16] = f2bf(acc[mf][nf][r] * inv);
      }
    }
}

// ---------------- im2col for 3x3 pad-1 conv: g[B,28,28,512](bf16) -> im[6272, 4608] ----------------
__global__ __launch_bounds__(256) void k_im2col(const u16* __restrict__ g, u16* __restrict__ im){
  int idx = blockIdx.x * 256 + threadIdx.x;
  int p  = idx / 576;
  int c8 = idx - p * 576;
  int k0 = c8 << 3;
  int t9 = k0 >> 9;
  int ci = k0 & 511;
  int ky = t9 / 3, kx = t9 - ky * 3;
  int bb = p / 784;
  int s = p - bb * 784;
  int h = s / 28, w = s - h * 28;
  int hh = h + ky - 1, ww = w + kx - 1;
  uint4 val = make_uint4(0u, 0u, 0u, 0u);
  if ((unsigned)hh < 28u && (unsigned)ww < 28u)
    val = *(const uint4*)&g[(((size_t)(bb * 28 + hh)) * 28 + ww) * 512 + ci];
  *(uint4*)&im[(size_t)p * 4608 + k0] = val;
}

// ---------------- orchestration ----------------
extern "C" void kernel_launch(void* const* d_in, const int* in_sizes, int n_in,
                              void* d_out, int out_size, void* d_ws, size_t ws_size,
                              hipStream_t stream)
{
  (void)in_sizes; (void)n_in; (void)out_size; (void)ws_size;
  const float* x      = (const float*)d_in[0];
  const float* n1w    = (const float*)d_in[1];
  const float* n1b    = (const float*)d_in[2];
  const float* qkv_w  = (const float*)d_in[3];
  const float* qkv_b  = (const float*)d_in[4];
  const float* proj_w = (const float*)d_in[5];
  const float* proj_b = (const float*)d_in[6];
  const float* rel_h  = (const float*)d_in[7];
  const float* rel_w  = (const float*)d_in[8];
  const float* n2w    = (const float*)d_in[9];
  const float* n2b    = (const float*)d_in[10];
  const float* fc1_w  = (const float*)d_in[11];
  const float* fc1_b  = (const float*)d_in[12];
  const float* fc2_w  = (const float*)d_in[13];
  const float* fc2_b  = (const float*)d_in[14];
  const float* c1w    = (const float*)d_in[15];
  const float* l1w    = (const float*)d_in[16];
  const float* l1b    = (const float*)d_in[17];
  const float* c2w    = (const float*)d_in[18];
  const float* l2w    = (const float*)d_in[19];
  const float* l2b    = (const float*)d_in[20];
  const float* c3w    = (const float*)d_in[21];
  const float* l3w    = (const float*)d_in[22];
  const float* l3b    = (const float*)d_in[23];

  char* ws = (char*)d_ws;
  size_t off = 0;
  auto alloc = [&](size_t bytes) -> void* {
    void* p = ws + off; off += (bytes + 255) & ~(size_t)255; return p;
  };
  const size_t M = 6272;
  u16* qkvT  = (u16*)alloc((size_t)3072 * 1024 * 2);
  u16* projT = (u16*)alloc((size_t)1024 * 1024 * 2);
  u16* fc1T  = (u16*)alloc((size_t)4096 * 1024 * 2);
  u16* fc2T  = (u16*)alloc((size_t)1024 * 4096 * 2);
  u16* c1T   = (u16*)alloc((size_t)512 * 1024 * 2);
  u16* c2T   = (u16*)alloc((size_t)512 * 4608 * 2);
  u16* c3T   = (u16*)alloc((size_t)1024 * 512 * 2);
  u16* qkvbuf = (u16*)alloc(M * 3072 * 2);
  u16* attn   = (u16*)alloc(M * 1024 * 2);
  u16* xn     = (u16*)alloc(M * 1024 * 2);
  float* x1   = (float*)alloc(M * 1024 * 4);
  u16* x2b    = (u16*)alloc(M * 1024 * 2);
  u16* c1buf  = (u16*)alloc(M * 512 * 2);
  u16* g1buf  = (u16*)alloc(M * 512 * 2);
  u16* hmlp   = qkvbuf;
  u16* im     = qkvbuf;
  u16* xn2    = xn;
  u16* c2buf  = c1buf;
  u16* g2buf  = g1buf;
  u16* c3buf  = attn;

  dim3 blk(256);
  k_transpose<<<dim3(3072/32, 1024/32), blk, 0, stream>>>(qkv_w, qkvT, 1024, 3072);
  k_transpose<<<dim3(1024/32, 1024/32), blk, 0, stream>>>(proj_w, projT, 1024, 1024);
  k_transpose<<<dim3(4096/32, 1024/32), blk, 0, stream>>>(fc1_w, fc1T, 1024, 4096);
  k_transpose<<<dim3(1024/32, 4096/32), blk, 0, stream>>>(fc2_w, fc2T, 4096, 1024);
  k_transpose<<<dim3(512/32, 1024/32),  blk, 0, stream>>>(c1w, c1T, 1024, 512);
  k_transpose<<<dim3(512/32, 4608/32),  blk, 0, stream>>>(c2w, c2T, 4608, 512);
  k_transpose<<<dim3(1024/32, 512/32),  blk, 0, stream>>>(c3w, c3T, 512, 1024);

  k_layernorm<true,false><<<6272, blk, 0, stream>>>(x, n1w, n1b, xn, 1024, 1e-5f);
  k_gemm<true,false,false,true,false><<<dim3(24,49), blk, 0, stream>>>(
      xn, qkvT, qkv_b, nullptr, qkvbuf, nullptr, 3072, 1024);
  k_attn3<<<896, blk, 0, stream>>>(qkvbuf, rel_h, rel_w, attn);
  k_gemm<true,false,true,false,true><<<dim3(8,49), blk, 0, stream>>>(
      attn, projT, proj_b, x, nullptr, x1, 1024, 1024);
  k_layernorm<true,false><<<6272, blk, 0, stream>>>(x1, n2w, n2b, xn2, 1024, 1e-5f);
  k_gemm<true,true,false,true,false><<<dim3(32,49), blk, 0, stream>>>(
      xn2, fc1T, fc1_b, nullptr, hmlp, nullptr, 4096, 1024);
  // fc2 + residual(x1) -> x2b bf16 only (fp32 x2 dropped; k_final reads bf16)
  k_gemm<true,false,true,true,false><<<dim3(8,49), blk, 0, stream>>>(
      hmlp, fc2T, fc2_b, x1, x2b, nullptr, 1024, 4096);
  k_gemm<false,false,false,true,false><<<dim3(4,49), blk, 0, stream>>>(
      x2b, c1T, nullptr, nullptr, c1buf, nullptr, 512, 1024);
  k_layernorm<false,true><<<6272, blk, 0, stream>>>(c1buf, l1w, l1b, g1buf, 512, 1e-6f);
  k_im2col<<<14112, blk, 0, stream>>>(g1buf, im);
  k_gemm<false,false,false,true,false><<<dim3(4,49), blk, 0, stream>>>(
      im, c2T, nullptr, nullptr, c2buf, nullptr, 512, 4608);
  k_layernorm<false,true><<<6272, blk, 0, stream>>>(c2buf, l2w, l2b, g2buf, 512, 1e-6f);
  k_gemm<false,false,false,true,false><<<dim3(8,49), blk, 0, stream>>>(
      g2buf, c3T, nullptr, nullptr, c3buf, nullptr, 1024, 512);
  k_final<<<6272, blk, 0, stream>>>(c3buf, x2b, l3w, l3b, (float*)d_out);
}